// Round 5
// baseline (487.916 us; speedup 1.0000x reference)
//
#include <hip/hip_runtime.h>
#include <math.h>

// Problem constants
#define NB 48      // batch*nodes
#define HD 256     // hidden
#define TS 512     // timesteps
// 2T-1 = 1023 relative positions

typedef __bf16 bf16x8 __attribute__((ext_vector_type(8)));
typedef float  f32x4  __attribute__((ext_vector_type(4)));

__device__ inline unsigned short f2b(float f) {       // f32 -> bf16 bits, RNE
  union { float f; unsigned u; } v; v.f = f;
  unsigned r = v.u + 0x7fff + ((v.u >> 16) & 1);
  return (unsigned short)(r >> 16);
}
__device__ inline float b2f(unsigned short u) {
  union { unsigned u; float f; } v; v.u = ((unsigned)u) << 16;
  return v.f;
}

// ---------------------------------------------------------------------------
// emb_rel[r][c]: hi bf16 [1023][256], lo bf16 [1023][256] (residual),
// transposed hi [256][1024] (pad col zeroed)
// ---------------------------------------------------------------------------
__global__ __launch_bounds__(256) void k_embrel(
    const float* __restrict__ teW, const float* __restrict__ teb,
    unsigned short* __restrict__ embB, unsigned short* __restrict__ embLo,
    unsigned short* __restrict__ embT)
{
  __shared__ float e[256];
  const int r = blockIdx.x;        // 0..1022
  const int tid = threadIdx.x;
  const float rel = (float)(r - (TS - 1));
  if (tid < 128) {
    float f = expf((float)tid * (-9.210340371976184f / 127.0f)); // -ln(1e4)/(half-1)
    float ang = rel * f;
    e[tid] = sinf(ang);
    e[tid + 128] = cosf(ang);
  }
  __syncthreads();
  float acc = teb[tid];
  for (int kk = 0; kk < 256; ++kk)
    acc = fmaf(e[kk], teW[kk * 256 + tid], acc);
  unsigned short hv = f2b(acc);
  embB[r * 256 + tid] = hv;
  embLo[r * 256 + tid] = f2b(acc - b2f(hv));
  embT[(size_t)tid * 1024 + r] = hv;
  if (r == 0) embT[(size_t)tid * 1024 + 1023] = 0;  // pad col: keep finite
}

// ---------------------------------------------------------------------------
// h [48,256,512] fp32  ->  hmB [24576][256] bf16   (hm[m,c] = h[b,c,t])
// ---------------------------------------------------------------------------
__global__ __launch_bounds__(256) void k_prep_h(
    const float* __restrict__ h, unsigned short* __restrict__ hmB)
{
  __shared__ float t[32 * 132];
  const int t0 = blockIdx.x * 128, c0 = blockIdx.y * 32, b = blockIdx.z;
  const int tid = threadIdx.x;
#pragma unroll
  for (int i = 0; i < 4; ++i) {
    int cl = i * 8 + (tid >> 5);           // 0..31
    int t4 = (tid & 31) * 4;               // 0..124
    float4 v = *(const float4*)&h[((size_t)b * 256 + c0 + cl) * 512 + t0 + t4];
    t[cl * 132 + t4 + 0] = v.x; t[cl * 132 + t4 + 1] = v.y;
    t[cl * 132 + t4 + 2] = v.z; t[cl * 132 + t4 + 3] = v.w;
  }
  __syncthreads();
#pragma unroll
  for (int i = 0; i < 16; ++i) {
    int tl = i * 8 + (tid >> 5);           // 0..127
    int cl = tid & 31;
    hmB[((size_t)b * 512 + t0 + tl) * 256 + c0 + cl] = f2b(t[cl * 132 + tl]);
  }
}

// ---------------------------------------------------------------------------
// Weights fp32 [K=256][N=256] -> bf16 transposed [N][K], 7 matrices
// ---------------------------------------------------------------------------
__global__ __launch_bounds__(256) void k_prep_w(
    const float* __restrict__ w0, const float* __restrict__ w1,
    const float* __restrict__ w2, const float* __restrict__ w3,
    const float* __restrict__ w4, const float* __restrict__ w5,
    const float* __restrict__ w6, unsigned short* __restrict__ WtB)
{
  __shared__ float t[64 * 68];
  const int mat = blockIdx.z;
  const float* W = (mat == 0) ? w0 : (mat == 1) ? w1 : (mat == 2) ? w2 :
                   (mat == 3) ? w3 : (mat == 4) ? w4 : (mat == 5) ? w5 : w6;
  unsigned short* dst = WtB + (size_t)mat * 65536;
  const int k0 = blockIdx.x * 64, n0 = blockIdx.y * 64;
  const int tid = threadIdx.x;
#pragma unroll
  for (int i = 0; i < 4; ++i) {
    int kr = i * 16 + (tid >> 4);          // 0..63 local k
    int nc = (tid & 15) * 4;               // 0..60 local n
    float4 v = *(const float4*)&W[(size_t)(k0 + kr) * 256 + n0 + nc];
    t[kr * 68 + nc + 0] = v.x; t[kr * 68 + nc + 1] = v.y;
    t[kr * 68 + nc + 2] = v.z; t[kr * 68 + nc + 3] = v.w;
  }
  __syncthreads();
#pragma unroll
  for (int i = 0; i < 4; ++i) {
    int nr = i * 16 + (tid >> 4);          // local n
    int kc = (tid & 15) * 4;               // local k
#pragma unroll
    for (int j = 0; j < 4; ++j)
      dst[(size_t)(n0 + nr) * 256 + k0 + kc + j] = f2b(t[(kc + j) * 68 + nr]);
  }
}

// ---------------------------------------------------------------------------
// V bf16 [24576][256] -> Vt bf16 [48][256][512]
// ---------------------------------------------------------------------------
__global__ __launch_bounds__(256) void k_prep_vt(
    const unsigned short* __restrict__ vB, unsigned short* __restrict__ vtB)
{
  __shared__ unsigned short tt[64][68];
  const int s0 = blockIdx.x * 64, h0 = blockIdx.y * 64, b = blockIdx.z;
  const int tid = threadIdx.x;
#pragma unroll
  for (int i = 0; i < 4; ++i) {
    int r = i * 16 + (tid >> 4);
    int c = (tid & 15) * 4;
    ushort4 v = *(const ushort4*)&vB[((size_t)(b * 512 + s0 + r) << 8) + h0 + c];
    tt[r][c + 0] = v.x; tt[r][c + 1] = v.y; tt[r][c + 2] = v.z; tt[r][c + 3] = v.w;
  }
  __syncthreads();
#pragma unroll
  for (int i = 0; i < 4; ++i) {
    int hr = i * 16 + (tid >> 4);
    int sc = (tid & 15) * 4;
    ushort4 o;
    o.x = tt[sc + 0][hr]; o.y = tt[sc + 1][hr];
    o.z = tt[sc + 2][hr]; o.w = tt[sc + 3][hr];
    *(ushort4*)&vtB[((size_t)(b * 256 + h0 + hr) << 9) + s0 + sc] = o;
  }
}

// ---------------------------------------------------------------------------
// bf16 MFMA GEMM, 2-job batched via blockIdx.z:
//   C[M,256] = act(A[M,256] @ Wt^T + bias); outB bf16 hi, outL bf16 lo (opt)
// ---------------------------------------------------------------------------
struct GJob {
  const unsigned short* A; const unsigned short* Wt; const float* bias;
  unsigned short* outB; unsigned short* outL;
};
struct GJobs { GJob j[2]; };

template<int ACT>
__global__ __launch_bounds__(256) void k_gemm(GJobs jobs)
{
  __shared__ uint4 As4[2048];   // 32 KB
  __shared__ uint4 Ws4[2048];   // 32 KB
  char* AsB = (char*)As4;
  char* WsB = (char*)Ws4;

  const GJob jb = jobs.j[blockIdx.z];

  const int tid  = threadIdx.x;
  const int lane = tid & 63;
  const int w    = tid >> 6;
  const int wr   = w >> 1, wc = w & 1;
  const int rq   = lane & 15;
  const int kq   = lane >> 4;

  const int m0 = blockIdx.x * 128;
  const int n0 = blockIdx.y * 128;
  const char* Ag = (const char*)jb.A  + (size_t)m0 * 512;
  const char* Wg = (const char*)jb.Wt + (size_t)n0 * 512;

  f32x4 acc[4][4];
#pragma unroll
  for (int mi = 0; mi < 4; ++mi)
#pragma unroll
    for (int ni = 0; ni < 4; ++ni)
      acc[mi][ni] = (f32x4){0.f, 0.f, 0.f, 0.f};

  for (int kt = 0; kt < 2; ++kt) {
    __syncthreads();
#pragma unroll
    for (int i = 0; i < 8; ++i) {
      int c = i * 256 + tid;
      int row = c >> 4;
      int colb = (c & 15) * 16;
      int sw = colb ^ ((row & 7) << 4);
      *(uint4*)(AsB + row * 256 + sw) =
          *(const uint4*)(Ag + (size_t)row * 512 + kt * 256 + colb);
      *(uint4*)(WsB + row * 256 + sw) =
          *(const uint4*)(Wg + (size_t)row * 512 + kt * 256 + colb);
    }
    __syncthreads();

#pragma unroll
    for (int kk = 0; kk < 4; ++kk) {
      const int kb = kk * 64 + kq * 16;
      bf16x8 af[4], bfr[4];
#pragma unroll
      for (int mi = 0; mi < 4; ++mi) {
        int row = wr * 64 + mi * 16 + rq;
        af[mi] = *(const bf16x8*)(AsB + row * 256 + (kb ^ ((row & 7) << 4)));
      }
#pragma unroll
      for (int ni = 0; ni < 4; ++ni) {
        int row = wc * 64 + ni * 16 + rq;
        bfr[ni] = *(const bf16x8*)(WsB + row * 256 + (kb ^ ((row & 7) << 4)));
      }
#pragma unroll
      for (int mi = 0; mi < 4; ++mi)
#pragma unroll
        for (int ni = 0; ni < 4; ++ni)
          acc[mi][ni] = __builtin_amdgcn_mfma_f32_16x16x32_bf16(
              af[mi], bfr[ni], acc[mi][ni], 0, 0, 0);
    }
  }

  float bv[4];
#pragma unroll
  for (int ni = 0; ni < 4; ++ni)
    bv[ni] = jb.bias[n0 + wc * 64 + ni * 16 + rq];

#pragma unroll
  for (int mi = 0; mi < 4; ++mi) {
#pragma unroll
    for (int ni = 0; ni < 4; ++ni) {
      const int n = n0 + wc * 64 + ni * 16 + rq;
#pragma unroll
      for (int j = 0; j < 4; ++j) {
        const int m = m0 + wr * 64 + mi * 16 + kq * 4 + j;
        float vl = acc[mi][ni][j] + bv[ni];
        if (ACT) vl = vl / (1.0f + __expf(-vl));
        unsigned short hv = f2b(vl);
        jb.outB[(size_t)m * 256 + n] = hv;
        if (jb.outL) jb.outL[(size_t)m * 256 + n] = f2b(vl - b2f(hv));
      }
    }
  }
}

// ---------------------------------------------------------------------------
// vx[m] = hidX[m,:] (bf16) @ xW2 + xb2
// ---------------------------------------------------------------------------
__global__ __launch_bounds__(256) void k_vx2(
    const unsigned short* __restrict__ hid,
    const float* __restrict__ xW2, const float* __restrict__ xb2,
    float* __restrict__ vx)
{
  const int m0 = blockIdx.x * 32;
  const int tid = threadIdx.x;
  const int tr = tid >> 3, tc = tid & 7;
  const unsigned short* row = hid + (size_t)(m0 + tr) * 256 + tc * 32;
  float acc = 0.0f;
#pragma unroll
  for (int i = 0; i < 4; ++i) {
    uint4 r = *(const uint4*)&row[i * 8];
    const unsigned rr[4] = {r.x, r.y, r.z, r.w};
#pragma unroll
    for (int jj = 0; jj < 4; ++jj) {
      float lo = b2f((unsigned short)(rr[jj] & 0xffff));
      float hi = b2f((unsigned short)(rr[jj] >> 16));
      acc = fmaf(lo, xW2[tc * 32 + i * 8 + 2 * jj + 0], acc);
      acc = fmaf(hi, xW2[tc * 32 + i * 8 + 2 * jj + 1], acc);
    }
  }
  acc += __shfl_xor(acc, 1);
  acc += __shfl_xor(acc, 2);
  acc += __shfl_xor(acc, 4);
  if (tc == 0) vx[m0 + tr] = acc + xb2[0];
}

// ---------------------------------------------------------------------------
// MFMA fused attention, 34 KB LDS (4 blocks/CU). Block = (b, 16 t-rows).
//  phase1: S = Q@K^T + band(Q@emb^T), hi/lo-compensated, accumulated
//          DIRECTLY in S (no Rl scratch): acc -> S, lgkmcnt fence, RMW racc.
//  softmax fp32 in regs (+ x-update); Pb/Pe ALIAS S (S dead after p-load).
//  phase2: O = P@Vt + Pe@embT-band.
// Grid 1D 1536, XCD-swizzled: all 32 t-tiles of one b on one XCD (id%8).
// LDS: S[16][524]f32 (33536 B)  UNION  { Pb[16][520] | Pe[16][544] } (34048 B)
//      sml[16] at +34048.  Total 34112 B.
// ---------------------------------------------------------------------------
__global__ __launch_bounds__(256, 4) void k_attn3(
    const float* __restrict__ xin, const float* __restrict__ hin,
    const unsigned short* __restrict__ qB, const unsigned short* __restrict__ qLo,
    const unsigned short* __restrict__ kB, const unsigned short* __restrict__ kLo,
    const unsigned short* __restrict__ vtB, const float* __restrict__ vxm,
    const unsigned short* __restrict__ embB, const unsigned short* __restrict__ embLo,
    const unsigned short* __restrict__ embT,
    float* __restrict__ xout, float* __restrict__ hout)
{
  __shared__ char smem[34112];
  float* S  = (float*)smem;                              // [16][524]
  unsigned short* Pb = (unsigned short*)smem;            // [16][520], after S dies
  unsigned short* Pe = (unsigned short*)(smem + 16640);  // [16][544]
  float* sml = (float*)(smem + 34048);                   // [16]

  const int tid  = threadIdx.x;
  const int lane = tid & 63;
  const int w    = tid >> 6;
  const int rq   = lane & 15;
  const int kq   = lane >> 4;
  // XCD swizzle: id = xcd + 8*(bx + 32*bgrp); b = xcd + 8*bgrp, t0 = bx*16
  const int id = blockIdx.x;
  const int t0 = ((id >> 3) & 31) * 16;
  const int b  = (id & 7) + 8 * (id >> 8);
  const int sw = w * 128;          // this wave's s-offset (phase 1)

  // ---- Q fragments hi+lo (held through phase 1) ----
  bf16x8 qh[8], ql[8];
  {
    const size_t qoff = ((size_t)(b * TS + t0 + rq) << 8) + kq * 8;
#pragma unroll
    for (int ks = 0; ks < 8; ++ks) {
      qh[ks] = *(const bf16x8*)(qB  + qoff + ks * 32);
      ql[ks] = *(const bf16x8*)(qLo + qoff + ks * 32);
    }
  }

  // ---- phase 1a: QK^T for s in [sw, sw+128), 3-term compensated ----
  f32x4 acc[8];
#pragma unroll
  for (int ni = 0; ni < 8; ++ni) acc[ni] = (f32x4){0.f, 0.f, 0.f, 0.f};
  {
    const size_t koff = ((size_t)(b * TS + sw + rq) << 8) + kq * 8;
    const unsigned short* kp  = kB  + koff;
    const unsigned short* kpl = kLo + koff;
#pragma unroll
    for (int ks = 0; ks < 8; ++ks) {
#pragma unroll
      for (int ni = 0; ni < 8; ++ni) {
        bf16x8 kh = *(const bf16x8*)(kp  + ni * 4096 + ks * 32);
        bf16x8 kl = *(const bf16x8*)(kpl + ni * 4096 + ks * 32);
        acc[ni] = __builtin_amdgcn_mfma_f32_16x16x32_bf16(qh[ks], kh, acc[ni], 0, 0, 0);
        acc[ni] = __builtin_amdgcn_mfma_f32_16x16x32_bf16(ql[ks], kh, acc[ni], 0, 0, 0);
        acc[ni] = __builtin_amdgcn_mfma_f32_16x16x32_bf16(qh[ks], kl, acc[ni], 0, 0, 0);
      }
    }
  }

  // ---- phase 1b: racc[t'][r_local] = Q . embband^T (143-wide band, 9 frags)
  f32x4 racc[9];
#pragma unroll
  for (int ni = 0; ni < 9; ++ni) racc[ni] = (f32x4){0.f, 0.f, 0.f, 0.f};
  const int rbR = t0 - sw + 384;            // r_global = rbR + r_local
  {
    const unsigned short *ep[9], *epl[9];
#pragma unroll
    for (int ni = 0; ni < 9; ++ni) {
      int rr = rbR + ni * 16 + rq;
      if (rr > 1022) rr = 1022;             // only r_local=143 (never gathered)
      ep[ni]  = embB  + ((size_t)rr << 8) + kq * 8;
      epl[ni] = embLo + ((size_t)rr << 8) + kq * 8;
    }
#pragma unroll
    for (int ks = 0; ks < 8; ++ks) {
#pragma unroll
      for (int ni = 0; ni < 9; ++ni) {
        bf16x8 eh = *(const bf16x8*)(ep[ni]  + ks * 32);
        bf16x8 el = *(const bf16x8*)(epl[ni] + ks * 32);
        racc[ni] = __builtin_amdgcn_mfma_f32_16x16x32_bf16(qh[ks], eh, racc[ni], 0, 0, 0);
        racc[ni] = __builtin_amdgcn_mfma_f32_16x16x32_bf16(ql[ks], eh, racc[ni], 0, 0, 0);
        racc[ni] = __builtin_amdgcn_mfma_f32_16x16x32_bf16(qh[ks], el, racc[ni], 0, 0, 0);
      }
    }
  }

  // ---- write acc -> S (wave-private window), fence, RMW racc into S ----
  // slot (tp, slw): acc element (ni=slw>>4, rq=slw&15, j=tp&3, kq=tp>>2);
  // racc element for it: r_local = tp+127-slw  ->  (ni=r_local>>4, rq=r_local&15).
  // Both bijective -> each slot written once, RMW'd by exactly one lane.
#pragma unroll
  for (int ni = 0; ni < 8; ++ni)
#pragma unroll
    for (int j = 0; j < 4; ++j)
      S[(kq * 4 + j) * 524 + sw + ni * 16 + rq] = acc[ni][j];
  asm volatile("s_waitcnt lgkmcnt(0)" ::: "memory");  // same-wave LDS visibility
  __builtin_amdgcn_sched_barrier(0);                  // rule #18: pin the fence
#pragma unroll
  for (int ni = 0; ni < 9; ++ni)
#pragma unroll
    for (int j = 0; j < 4; ++j) {
      int tp  = kq * 4 + j;
      int slw = tp + 127 - (ni * 16 + rq);  // s-window slot this element feeds
      if (slw >= 0 && slw < 128)
        S[tp * 524 + sw + slw] += racc[ni][j];
    }
  __syncthreads();   // B1: S complete across waves

  // ---- softmax (16 threads per row) + x-update ----
  const int row = tid >> 4, tx = tid & 15;
  float p[32];
  float mx = -3.0e38f, l = 0.f;
  {
    const float* Srow = S + row * 524 + tx * 4;
#pragma unroll
    for (int i = 0; i < 8; ++i) {
      float4 v = *(const float4*)(Srow + i * 64);
      p[4*i+0] = v.x; p[4*i+1] = v.y; p[4*i+2] = v.z; p[4*i+3] = v.w;
    }
#pragma unroll
    for (int i = 0; i < 32; ++i) mx = fmaxf(mx, p[i]);
    mx = fmaxf(mx, __shfl_xor(mx, 1)); mx = fmaxf(mx, __shfl_xor(mx, 2));
    mx = fmaxf(mx, __shfl_xor(mx, 4)); mx = fmaxf(mx, __shfl_xor(mx, 8));
#pragma unroll
    for (int i = 0; i < 32; ++i) { p[i] = __expf(p[i] - mx); l += p[i]; }
    l += __shfl_xor(l, 1); l += __shfl_xor(l, 2);
    l += __shfl_xor(l, 4); l += __shfl_xor(l, 8);
  }
  const float invl = 1.0f / l;
  {
    const float* vxp = vxm + b * TS;
    const float* xp  = xin + (size_t)b * 3 * TS;
    float wsum = 0.f, xa0 = 0.f, xa1 = 0.f, xa2 = 0.f;
#pragma unroll
    for (int i = 0; i < 8; ++i) {
      int s = i * 64 + tx * 4;
      float4 vv = *(const float4*)(vxp + s);
      float4 x0 = *(const float4*)(xp + s);
      float4 x1 = *(const float4*)(xp + TS + s);
      float4 x2 = *(const float4*)(xp + 2 * TS + s);
      float wv;
      wv = p[4*i+0] * vv.x; wsum += wv; xa0 = fmaf(wv, x0.x, xa0); xa1 = fmaf(wv, x1.x, xa1); xa2 = fmaf(wv, x2.x, xa2);
      wv = p[4*i+1] * vv.y; wsum += wv; xa0 = fmaf(wv, x0.y, xa0); xa1 = fmaf(wv, x1.y, xa1); xa2 = fmaf(wv, x2.y, xa2);
      wv = p[4*i+2] * vv.z; wsum += wv; xa0 = fmaf(wv, x0.z, xa0); xa1 = fmaf(wv, x1.z, xa1); xa2 = fmaf(wv, x2.z, xa2);
      wv = p[4*i+3] * vv.w; wsum += wv; xa0 = fmaf(wv, x0.w, xa0); xa1 = fmaf(wv, x1.w, xa1); xa2 = fmaf(wv, x2.w, xa2);
    }
    wsum += __shfl_xor(wsum, 1); wsum += __shfl_xor(wsum, 2);
    wsum += __shfl_xor(wsum, 4); wsum += __shfl_xor(wsum, 8);
    xa0 += __shfl_xor(xa0, 1); xa0 += __shfl_xor(xa0, 2); xa0 += __shfl_xor(xa0, 4); xa0 += __shfl_xor(xa0, 8);
    xa1 += __shfl_xor(xa1, 1); xa1 += __shfl_xor(xa1, 2); xa1 += __shfl_xor(xa1, 4); xa1 += __shfl_xor(xa1, 8);
    xa2 += __shfl_xor(xa2, 1); xa2 += __shfl_xor(xa2, 2); xa2 += __shfl_xor(xa2, 4); xa2 += __shfl_xor(xa2, 8);
    if (tx == 0) {
      int t = t0 + row;
      float ws = wsum * invl;
      xout[(b * 3 + 0) * TS + t] = xp[t]           * (1.0f + ws) - xa0 * invl;
      xout[(b * 3 + 1) * TS + t] = xp[TS + t]      * (1.0f + ws) - xa1 * invl;
      xout[(b * 3 + 2) * TS + t] = xp[2 * TS + t]  * (1.0f + ws) - xa2 * invl;
      sml[row] = invl;
    }
  }
  __syncthreads();   // B2: everyone done reading S -> Pb/Pe may overwrite

  // ---- zero Pe (17408 B = 4352 words, 17/thread) ----
  {
    unsigned int* pz = (unsigned int*)Pe;
#pragma unroll
    for (int i = 0; i < 17; ++i) pz[i * 256 + tid] = 0u;
  }
  __syncthreads();   // B2b: Pe zeroed before scatter

  // ---- scatter P -> Pb (row-major) and Pe (banded: r_local = row+511-s) ----
  {
    unsigned short* pbrow = Pb + row * 520 + tx * 4;
    unsigned short* perow = Pe + row * 544 + row + 511;
#pragma unroll
    for (int i = 0; i < 8; ++i) {
      int s = i * 64 + tx * 4;
      ushort4 pu;
      pu.x = f2b(p[4*i+0]); pu.y = f2b(p[4*i+1]);
      pu.z = f2b(p[4*i+2]); pu.w = f2b(p[4*i+3]);
      *(ushort4*)(pbrow + i * 64) = pu;
      perow[-(s + 0)] = pu.x; perow[-(s + 1)] = pu.y;
      perow[-(s + 2)] = pu.z; perow[-(s + 3)] = pu.w;
    }
  }
  __syncthreads();   // B3: Pb/Pe/sml ready

  // ---- phase 2: O[t'][h] = P@Vt + Pe@embT-band, h-slice per wave ----
  const int n0 = w * 64;
  f32x4 oacc[4];
#pragma unroll
  for (int ni = 0; ni < 4; ++ni) oacc[ni] = (f32x4){0.f, 0.f, 0.f, 0.f};
  {
    const unsigned short* pbp = Pb + rq * 520 + kq * 8;
    const unsigned short* vtp = vtB + ((size_t)(b * 256 + n0 + rq) << 9) + kq * 8;
#pragma unroll
    for (int ks = 0; ks < 16; ++ks) {
      bf16x8 pa = *(const bf16x8*)(pbp + ks * 32);
      bf16x8 vf[4];
#pragma unroll
      for (int ni = 0; ni < 4; ++ni) vf[ni] = *(const bf16x8*)(vtp + ni * 8192 + ks * 32);
#pragma unroll
      for (int ni = 0; ni < 4; ++ni)
        oacc[ni] = __builtin_amdgcn_mfma_f32_16x16x32_bf16(pa, vf[ni], oacc[ni], 0, 0, 0);
    }
  }
  {
    const unsigned short* pep = Pe + rq * 544 + kq * 8;
    const unsigned short* etp = embT + ((size_t)(n0 + rq) << 10);
#pragma unroll
    for (int ks = 0; ks < 17; ++ks) {
      bf16x8 pa = *(const bf16x8*)(pep + ks * 32);
      int rg = t0 + ks * 32 + kq * 8;            // r_global = t0 + r_local
      if (rg > 1016) rg = 1016;                  // clamp only where Pe is zero
      bf16x8 ef[4];
#pragma unroll
      for (int ni = 0; ni < 4; ++ni) ef[ni] = *(const bf16x8*)(etp + (ni << 14) + rg);
#pragma unroll
      for (int ni = 0; ni < 4; ++ni)
        oacc[ni] = __builtin_amdgcn_mfma_f32_16x16x32_bf16(pa, ef[ni], oacc[ni], 0, 0, 0);
    }
  }

  // ---- epilogue: normalize by 1/l, add h residual, coalesced float4 ----
  {
    float il0 = sml[kq * 4 + 0], il1 = sml[kq * 4 + 1];
    float il2 = sml[kq * 4 + 2], il3 = sml[kq * 4 + 3];
#pragma unroll
    for (int ni = 0; ni < 4; ++ni) {
      int hh = n0 + ni * 16 + rq;
      size_t off = (((size_t)(b * 256 + hh)) << 9) + t0 + kq * 4;
      float4 hv = *(const float4*)(hin + off);
      float4 ov;
      ov.x = hv.x + oacc[ni][0] * il0;
      ov.y = hv.y + oacc[ni][1] * il1;
      ov.z = hv.z + oacc[ni][2] * il2;
      ov.w = hv.w + oacc[ni][3] * il3;
      *(float4*)(hout + off) = ov;
    }
  }
}

// ---------------------------------------------------------------------------
extern "C" void kernel_launch(void* const* d_in, const int* in_sizes, int n_in,
                              void* d_out, int out_size, void* d_ws, size_t ws_size,
                              hipStream_t stream)
{
  const float* x   = (const float*)d_in[0];
  const float* h   = (const float*)d_in[1];
  const float* qW1 = (const float*)d_in[2];
  const float* qb1 = (const float*)d_in[3];
  const float* qW2 = (const float*)d_in[4];
  const float* qb2 = (const float*)d_in[5];
  const float* kW1 = (const float*)d_in[6];
  const float* kb1 = (const float*)d_in[7];
  const float* kW2 = (const float*)d_in[8];
  const float* kb2 = (const float*)d_in[9];
  const float* vW1 = (const float*)d_in[10];
  const float* vb1 = (const float*)d_in[11];
  const float* vW2 = (const float*)d_in[12];
  const float* vb2 = (const float*)d_in[13];
  const float* xW1 = (const float*)d_in[14];
  const float* xb1 = (const float*)d_in[15];
  const float* xW2 = (const float*)d_in[16];
  const float* xb2 = (const float*)d_in[17];
  const float* teW = (const float*)d_in[18];
  const float* teb = (const float*)d_in[19];

  // ws layout (bf16 except vx) ~116 MB; hidV aliases hidQ, hidX aliases hidK
  unsigned short* cur = (unsigned short*)d_ws;
  unsigned short* embB  = cur; cur += 1023 * 256;
  unsigned short* embLo = cur; cur += 1023 * 256;
  unsigned short* embT  = cur; cur += 256 * 1024;
  unsigned short* hmB   = cur; cur += (size_t)24576 * 256;
  unsigned short* WtB   = cur; cur += 7 * 65536;
  unsigned short* hidQ  = cur; cur += (size_t)24576 * 256;
  unsigned short* hidK  = cur; cur += (size_t)24576 * 256;
  unsigned short* qBp   = cur; cur += (size_t)24576 * 256;
  unsigned short* qLo   = cur; cur += (size_t)24576 * 256;
  unsigned short* kBp   = cur; cur += (size_t)24576 * 256;
  unsigned short* kLo   = cur; cur += (size_t)24576 * 256;
  unsigned short* vBp   = cur; cur += (size_t)24576 * 256;
  unsigned short* vtB   = cur; cur += (size_t)24576 * 256;
  float* vx = (float*)cur;                                // 24576 f32
  unsigned short* hidV = hidQ;   // dead after L2-q/k launch
  unsigned short* hidX = hidK;   // dead after L2-q/k launch

  float* xout = (float*)d_out;                // [48,3,512]
  float* hout = xout + NB * 3 * TS;           // [48,256,512]

  k_embrel<<<1023, 256, 0, stream>>>(teW, teb, embB, embLo, embT);
  k_prep_h<<<dim3(4, 8, 48), 256, 0, stream>>>(h, hmB);
  k_prep_w<<<dim3(4, 4, 7), 256, 0, stream>>>(qW1, qW2, kW1, kW2, vW1, vW2, xW1, WtB);

  // q,k layer 1 (fused launch), then layer 2 (fused, with lo residuals)
  {
    GJobs j1{{{hmB, WtB + 0 * 65536, qb1, hidQ, nullptr},
              {hmB, WtB + 2 * 65536, kb1, hidK, nullptr}}};
    k_gemm<1><<<dim3(192, 2, 2), 256, 0, stream>>>(j1);
    GJobs j2{{{hidQ, WtB + 1 * 65536, qb2, qBp, qLo},
              {hidK, WtB + 3 * 65536, kb2, kBp, kLo}}};
    k_gemm<0><<<dim3(192, 2, 2), 256, 0, stream>>>(j2);
  }
  // v MLP (hidV reuses hidQ), then x-MLP layer 1 (hidX reuses hidK)
  {
    GJobs j3{{{hmB, WtB + 4 * 65536, vb1, hidV, nullptr}, {}}};
    k_gemm<1><<<dim3(192, 2, 1), 256, 0, stream>>>(j3);
    GJobs j4{{{hidV, WtB + 5 * 65536, vb2, vBp, nullptr}, {}}};
    k_gemm<0><<<dim3(192, 2, 1), 256, 0, stream>>>(j4);
    GJobs j5{{{vBp, WtB + 6 * 65536, xb1, hidX, nullptr}, {}}};
    k_gemm<1><<<dim3(192, 2, 1), 256, 0, stream>>>(j5);
  }
  k_vx2<<<768, 256, 0, stream>>>(hidX, xW2, xb2, vx);
  k_prep_vt<<<dim3(8, 4, 48), 256, 0, stream>>>(vBp, vtB);

  k_attn3<<<1536, 256, 0, stream>>>(x, h, qBp, qLo, kBp, kLo, vtB, vx,
                                    embB, embLo, embT, xout, hout);
}

// Round 6
// 419.429 us; speedup vs baseline: 1.1633x; 1.1633x over previous
//
#include <hip/hip_runtime.h>
#include <math.h>

// Problem constants
#define NB 48      // batch*nodes
#define HD 256     // hidden
#define TS 512     // timesteps
// 2T-1 = 1023 relative positions

typedef __bf16 bf16x8 __attribute__((ext_vector_type(8)));
typedef float  f32x4  __attribute__((ext_vector_type(4)));

__device__ inline unsigned short f2b(float f) {       // f32 -> bf16 bits, RNE
  union { float f; unsigned u; } v; v.f = f;
  unsigned r = v.u + 0x7fff + ((v.u >> 16) & 1);
  return (unsigned short)(r >> 16);
}
__device__ inline float b2f(unsigned short u) {
  union { unsigned u; float f; } v; v.u = ((unsigned)u) << 16;
  return v.f;
}

// ---------------------------------------------------------------------------
// emb_rel[r][c]: hi bf16 [1023][256], lo bf16 [1023][256] (residual),
// transposed hi [256][1024] (pad col zeroed)
// ---------------------------------------------------------------------------
__global__ __launch_bounds__(256) void k_embrel(
    const float* __restrict__ teW, const float* __restrict__ teb,
    unsigned short* __restrict__ embB, unsigned short* __restrict__ embLo,
    unsigned short* __restrict__ embT)
{
  __shared__ float e[256];
  const int r = blockIdx.x;        // 0..1022
  const int tid = threadIdx.x;
  const float rel = (float)(r - (TS - 1));
  if (tid < 128) {
    float f = expf((float)tid * (-9.210340371976184f / 127.0f)); // -ln(1e4)/(half-1)
    float ang = rel * f;
    e[tid] = sinf(ang);
    e[tid + 128] = cosf(ang);
  }
  __syncthreads();
  float acc = teb[tid];
  for (int kk = 0; kk < 256; ++kk)
    acc = fmaf(e[kk], teW[kk * 256 + tid], acc);
  unsigned short hv = f2b(acc);
  embB[r * 256 + tid] = hv;
  embLo[r * 256 + tid] = f2b(acc - b2f(hv));
  embT[(size_t)tid * 1024 + r] = hv;
  if (r == 0) embT[(size_t)tid * 1024 + 1023] = 0;  // pad col: keep finite
}

// ---------------------------------------------------------------------------
// h [48,256,512] fp32  ->  hmB [24576][256] bf16   (hm[m,c] = h[b,c,t])
// ---------------------------------------------------------------------------
__global__ __launch_bounds__(256) void k_prep_h(
    const float* __restrict__ h, unsigned short* __restrict__ hmB)
{
  __shared__ float t[32 * 132];
  const int t0 = blockIdx.x * 128, c0 = blockIdx.y * 32, b = blockIdx.z;
  const int tid = threadIdx.x;
#pragma unroll
  for (int i = 0; i < 4; ++i) {
    int cl = i * 8 + (tid >> 5);           // 0..31
    int t4 = (tid & 31) * 4;               // 0..124
    float4 v = *(const float4*)&h[((size_t)b * 256 + c0 + cl) * 512 + t0 + t4];
    t[cl * 132 + t4 + 0] = v.x; t[cl * 132 + t4 + 1] = v.y;
    t[cl * 132 + t4 + 2] = v.z; t[cl * 132 + t4 + 3] = v.w;
  }
  __syncthreads();
#pragma unroll
  for (int i = 0; i < 16; ++i) {
    int tl = i * 8 + (tid >> 5);           // 0..127
    int cl = tid & 31;
    hmB[((size_t)b * 512 + t0 + tl) * 256 + c0 + cl] = f2b(t[cl * 132 + tl]);
  }
}

// ---------------------------------------------------------------------------
// Weights fp32 [K=256][N=256] -> bf16 transposed [N][K], 7 matrices
// ---------------------------------------------------------------------------
__global__ __launch_bounds__(256) void k_prep_w(
    const float* __restrict__ w0, const float* __restrict__ w1,
    const float* __restrict__ w2, const float* __restrict__ w3,
    const float* __restrict__ w4, const float* __restrict__ w5,
    const float* __restrict__ w6, unsigned short* __restrict__ WtB)
{
  __shared__ float t[64 * 68];
  const int mat = blockIdx.z;
  const float* W = (mat == 0) ? w0 : (mat == 1) ? w1 : (mat == 2) ? w2 :
                   (mat == 3) ? w3 : (mat == 4) ? w4 : (mat == 5) ? w5 : w6;
  unsigned short* dst = WtB + (size_t)mat * 65536;
  const int k0 = blockIdx.x * 64, n0 = blockIdx.y * 64;
  const int tid = threadIdx.x;
#pragma unroll
  for (int i = 0; i < 4; ++i) {
    int kr = i * 16 + (tid >> 4);          // 0..63 local k
    int nc = (tid & 15) * 4;               // 0..60 local n
    float4 v = *(const float4*)&W[(size_t)(k0 + kr) * 256 + n0 + nc];
    t[kr * 68 + nc + 0] = v.x; t[kr * 68 + nc + 1] = v.y;
    t[kr * 68 + nc + 2] = v.z; t[kr * 68 + nc + 3] = v.w;
  }
  __syncthreads();
#pragma unroll
  for (int i = 0; i < 4; ++i) {
    int nr = i * 16 + (tid >> 4);          // local n
    int kc = (tid & 15) * 4;               // local k
#pragma unroll
    for (int j = 0; j < 4; ++j)
      dst[(size_t)(n0 + nr) * 256 + k0 + kc + j] = f2b(t[(kc + j) * 68 + nr]);
  }
}

// ---------------------------------------------------------------------------
// V bf16 [24576][256] -> Vt bf16 [48][256][512]
// ---------------------------------------------------------------------------
__global__ __launch_bounds__(256) void k_prep_vt(
    const unsigned short* __restrict__ vB, unsigned short* __restrict__ vtB)
{
  __shared__ unsigned short tt[64][68];
  const int s0 = blockIdx.x * 64, h0 = blockIdx.y * 64, b = blockIdx.z;
  const int tid = threadIdx.x;
#pragma unroll
  for (int i = 0; i < 4; ++i) {
    int r = i * 16 + (tid >> 4);
    int c = (tid & 15) * 4;
    ushort4 v = *(const ushort4*)&vB[((size_t)(b * 512 + s0 + r) << 8) + h0 + c];
    tt[r][c + 0] = v.x; tt[r][c + 1] = v.y; tt[r][c + 2] = v.z; tt[r][c + 3] = v.w;
  }
  __syncthreads();
#pragma unroll
  for (int i = 0; i < 4; ++i) {
    int hr = i * 16 + (tid >> 4);
    int sc = (tid & 15) * 4;
    ushort4 o;
    o.x = tt[sc + 0][hr]; o.y = tt[sc + 1][hr];
    o.z = tt[sc + 2][hr]; o.w = tt[sc + 3][hr];
    *(ushort4*)&vtB[((size_t)(b * 256 + h0 + hr) << 9) + s0 + sc] = o;
  }
}

// ---------------------------------------------------------------------------
// bf16 MFMA GEMM, 2-job batched via blockIdx.z:
//   C[M,256] = act(A[M,256] @ Wt^T + bias); outB bf16 hi, outL bf16 lo (opt)
// ---------------------------------------------------------------------------
struct GJob {
  const unsigned short* A; const unsigned short* Wt; const float* bias;
  unsigned short* outB; unsigned short* outL;
};
struct GJobs { GJob j[2]; };

template<int ACT>
__global__ __launch_bounds__(256) void k_gemm(GJobs jobs)
{
  __shared__ uint4 As4[2048];   // 32 KB
  __shared__ uint4 Ws4[2048];   // 32 KB
  char* AsB = (char*)As4;
  char* WsB = (char*)Ws4;

  const GJob jb = jobs.j[blockIdx.z];

  const int tid  = threadIdx.x;
  const int lane = tid & 63;
  const int w    = tid >> 6;
  const int wr   = w >> 1, wc = w & 1;
  const int rq   = lane & 15;
  const int kq   = lane >> 4;

  const int m0 = blockIdx.x * 128;
  const int n0 = blockIdx.y * 128;
  const char* Ag = (const char*)jb.A  + (size_t)m0 * 512;
  const char* Wg = (const char*)jb.Wt + (size_t)n0 * 512;

  f32x4 acc[4][4];
#pragma unroll
  for (int mi = 0; mi < 4; ++mi)
#pragma unroll
    for (int ni = 0; ni < 4; ++ni)
      acc[mi][ni] = (f32x4){0.f, 0.f, 0.f, 0.f};

  for (int kt = 0; kt < 2; ++kt) {
    __syncthreads();
#pragma unroll
    for (int i = 0; i < 8; ++i) {
      int c = i * 256 + tid;
      int row = c >> 4;
      int colb = (c & 15) * 16;
      int sw = colb ^ ((row & 7) << 4);
      *(uint4*)(AsB + row * 256 + sw) =
          *(const uint4*)(Ag + (size_t)row * 512 + kt * 256 + colb);
      *(uint4*)(WsB + row * 256 + sw) =
          *(const uint4*)(Wg + (size_t)row * 512 + kt * 256 + colb);
    }
    __syncthreads();

#pragma unroll
    for (int kk = 0; kk < 4; ++kk) {
      const int kb = kk * 64 + kq * 16;
      bf16x8 af[4], bfr[4];
#pragma unroll
      for (int mi = 0; mi < 4; ++mi) {
        int row = wr * 64 + mi * 16 + rq;
        af[mi] = *(const bf16x8*)(AsB + row * 256 + (kb ^ ((row & 7) << 4)));
      }
#pragma unroll
      for (int ni = 0; ni < 4; ++ni) {
        int row = wc * 64 + ni * 16 + rq;
        bfr[ni] = *(const bf16x8*)(WsB + row * 256 + (kb ^ ((row & 7) << 4)));
      }
#pragma unroll
      for (int mi = 0; mi < 4; ++mi)
#pragma unroll
        for (int ni = 0; ni < 4; ++ni)
          acc[mi][ni] = __builtin_amdgcn_mfma_f32_16x16x32_bf16(
              af[mi], bfr[ni], acc[mi][ni], 0, 0, 0);
    }
  }

  float bv[4];
#pragma unroll
  for (int ni = 0; ni < 4; ++ni)
    bv[ni] = jb.bias[n0 + wc * 64 + ni * 16 + rq];

#pragma unroll
  for (int mi = 0; mi < 4; ++mi) {
#pragma unroll
    for (int ni = 0; ni < 4; ++ni) {
      const int n = n0 + wc * 64 + ni * 16 + rq;
#pragma unroll
      for (int j = 0; j < 4; ++j) {
        const int m = m0 + wr * 64 + mi * 16 + kq * 4 + j;
        float vl = acc[mi][ni][j] + bv[ni];
        if (ACT) vl = vl / (1.0f + __expf(-vl));
        unsigned short hv = f2b(vl);
        jb.outB[(size_t)m * 256 + n] = hv;
        if (jb.outL) jb.outL[(size_t)m * 256 + n] = f2b(vl - b2f(hv));
      }
    }
  }
}

// ---------------------------------------------------------------------------
// vx[m] = hidX[m,:] (bf16) @ xW2 + xb2
// ---------------------------------------------------------------------------
__global__ __launch_bounds__(256) void k_vx2(
    const unsigned short* __restrict__ hid,
    const float* __restrict__ xW2, const float* __restrict__ xb2,
    float* __restrict__ vx)
{
  const int m0 = blockIdx.x * 32;
  const int tid = threadIdx.x;
  const int tr = tid >> 3, tc = tid & 7;
  const unsigned short* row = hid + (size_t)(m0 + tr) * 256 + tc * 32;
  float acc = 0.0f;
#pragma unroll
  for (int i = 0; i < 4; ++i) {
    uint4 r = *(const uint4*)&row[i * 8];
    const unsigned rr[4] = {r.x, r.y, r.z, r.w};
#pragma unroll
    for (int jj = 0; jj < 4; ++jj) {
      float lo = b2f((unsigned short)(rr[jj] & 0xffff));
      float hi = b2f((unsigned short)(rr[jj] >> 16));
      acc = fmaf(lo, xW2[tc * 32 + i * 8 + 2 * jj + 0], acc);
      acc = fmaf(hi, xW2[tc * 32 + i * 8 + 2 * jj + 1], acc);
    }
  }
  acc += __shfl_xor(acc, 1);
  acc += __shfl_xor(acc, 2);
  acc += __shfl_xor(acc, 4);
  if (tc == 0) vx[m0 + tr] = acc + xb2[0];
}

// ---------------------------------------------------------------------------
// MFMA fused attention, 34 KB LDS. Block = (b, 16 t-rows), 4 waves.
// launch_bounds (256,2): round-4's proven register budget (124 VGPR, no
// spill) — (256,4) forced a 64-reg budget and spilled 250 MB to scratch.
// acc -> S is flushed BETWEEN phase 1a and 1b to cut peak live registers.
// Grid 1D 1536, XCD-swizzled: all 32 t-tiles of one b on one XCD (id%8).
// LDS: S[16][524]f32 (33536 B)  UNION  { Pb[16][520] | Pe[16][544] } (34048 B)
//      sml[16] at +34048.  Total 34112 B.
// ---------------------------------------------------------------------------
__global__ __launch_bounds__(256, 2) void k_attn3(
    const float* __restrict__ xin, const float* __restrict__ hin,
    const unsigned short* __restrict__ qB, const unsigned short* __restrict__ qLo,
    const unsigned short* __restrict__ kB, const unsigned short* __restrict__ kLo,
    const unsigned short* __restrict__ vtB, const float* __restrict__ vxm,
    const unsigned short* __restrict__ embB, const unsigned short* __restrict__ embLo,
    const unsigned short* __restrict__ embT,
    float* __restrict__ xout, float* __restrict__ hout)
{
  __shared__ char smem[34112];
  float* S  = (float*)smem;                              // [16][524]
  unsigned short* Pb = (unsigned short*)smem;            // [16][520], after S dies
  unsigned short* Pe = (unsigned short*)(smem + 16640);  // [16][544]
  float* sml = (float*)(smem + 34048);                   // [16]

  const int tid  = threadIdx.x;
  const int lane = tid & 63;
  const int w    = tid >> 6;
  const int rq   = lane & 15;
  const int kq   = lane >> 4;
  // XCD swizzle: id = xcd + 8*(bx + 32*bgrp); b = xcd + 8*bgrp, t0 = bx*16
  const int id = blockIdx.x;
  const int t0 = ((id >> 3) & 31) * 16;
  const int b  = (id & 7) + 8 * (id >> 8);
  const int sw = w * 128;          // this wave's s-offset (phase 1)

  // ---- Q fragments hi+lo (held through phase 1) ----
  bf16x8 qh[8], ql[8];
  {
    const size_t qoff = ((size_t)(b * TS + t0 + rq) << 8) + kq * 8;
#pragma unroll
    for (int ks = 0; ks < 8; ++ks) {
      qh[ks] = *(const bf16x8*)(qB  + qoff + ks * 32);
      ql[ks] = *(const bf16x8*)(qLo + qoff + ks * 32);
    }
  }

  // ---- phase 1a: QK^T for s in [sw, sw+128), 3-term compensated ----
  {
    f32x4 acc[8];
#pragma unroll
    for (int ni = 0; ni < 8; ++ni) acc[ni] = (f32x4){0.f, 0.f, 0.f, 0.f};
    const size_t koff = ((size_t)(b * TS + sw + rq) << 8) + kq * 8;
    const unsigned short* kp  = kB  + koff;
    const unsigned short* kpl = kLo + koff;
#pragma unroll
    for (int ks = 0; ks < 8; ++ks) {
#pragma unroll
      for (int ni = 0; ni < 8; ++ni) {
        bf16x8 kh = *(const bf16x8*)(kp  + ni * 4096 + ks * 32);
        bf16x8 kl = *(const bf16x8*)(kpl + ni * 4096 + ks * 32);
        acc[ni] = __builtin_amdgcn_mfma_f32_16x16x32_bf16(qh[ks], kh, acc[ni], 0, 0, 0);
        acc[ni] = __builtin_amdgcn_mfma_f32_16x16x32_bf16(ql[ks], kh, acc[ni], 0, 0, 0);
        acc[ni] = __builtin_amdgcn_mfma_f32_16x16x32_bf16(qh[ks], kl, acc[ni], 0, 0, 0);
      }
    }
    // flush acc -> S now (final values): frees 32 regs before racc goes live
#pragma unroll
    for (int ni = 0; ni < 8; ++ni)
#pragma unroll
      for (int j = 0; j < 4; ++j)
        S[(kq * 4 + j) * 524 + sw + ni * 16 + rq] = acc[ni][j];
  }

  // ---- phase 1b: racc[t'][r_local] = Q . embband^T (143-wide band, 9 frags)
  f32x4 racc[9];
#pragma unroll
  for (int ni = 0; ni < 9; ++ni) racc[ni] = (f32x4){0.f, 0.f, 0.f, 0.f};
  const int rbR = t0 - sw + 384;            // r_global = rbR + r_local
  {
    const unsigned short *ep[9], *epl[9];
#pragma unroll
    for (int ni = 0; ni < 9; ++ni) {
      int rr = rbR + ni * 16 + rq;
      if (rr > 1022) rr = 1022;             // only r_local=143 (never gathered)
      ep[ni]  = embB  + ((size_t)rr << 8) + kq * 8;
      epl[ni] = embLo + ((size_t)rr << 8) + kq * 8;
    }
#pragma unroll
    for (int ks = 0; ks < 8; ++ks) {
#pragma unroll
      for (int ni = 0; ni < 9; ++ni) {
        bf16x8 eh = *(const bf16x8*)(ep[ni]  + ks * 32);
        bf16x8 el = *(const bf16x8*)(epl[ni] + ks * 32);
        racc[ni] = __builtin_amdgcn_mfma_f32_16x16x32_bf16(qh[ks], eh, racc[ni], 0, 0, 0);
        racc[ni] = __builtin_amdgcn_mfma_f32_16x16x32_bf16(ql[ks], eh, racc[ni], 0, 0, 0);
        racc[ni] = __builtin_amdgcn_mfma_f32_16x16x32_bf16(qh[ks], el, racc[ni], 0, 0, 0);
      }
    }
  }

  // ---- fence, then RMW racc into S ----
  // slot (tp, slw): acc element (ni=slw>>4, rq=slw&15, j=tp&3, kq=tp>>2);
  // racc element for it: r_local = tp+127-slw  ->  (ni=r_local>>4, rq=r_local&15).
  // Both bijective -> each slot written once, RMW'd by exactly one lane.
  asm volatile("s_waitcnt lgkmcnt(0)" ::: "memory");  // same-wave LDS visibility
  __builtin_amdgcn_sched_barrier(0);                  // rule #18: pin the fence
#pragma unroll
  for (int ni = 0; ni < 9; ++ni)
#pragma unroll
    for (int j = 0; j < 4; ++j) {
      int tp  = kq * 4 + j;
      int slw = tp + 127 - (ni * 16 + rq);  // s-window slot this element feeds
      if (slw >= 0 && slw < 128)
        S[tp * 524 + sw + slw] += racc[ni][j];
    }
  __syncthreads();   // B1: S complete across waves

  // ---- softmax (16 threads per row) + x-update ----
  const int row = tid >> 4, tx = tid & 15;
  float p[32];
  float mx = -3.0e38f, l = 0.f;
  {
    const float* Srow = S + row * 524 + tx * 4;
#pragma unroll
    for (int i = 0; i < 8; ++i) {
      float4 v = *(const float4*)(Srow + i * 64);
      p[4*i+0] = v.x; p[4*i+1] = v.y; p[4*i+2] = v.z; p[4*i+3] = v.w;
    }
#pragma unroll
    for (int i = 0; i < 32; ++i) mx = fmaxf(mx, p[i]);
    mx = fmaxf(mx, __shfl_xor(mx, 1)); mx = fmaxf(mx, __shfl_xor(mx, 2));
    mx = fmaxf(mx, __shfl_xor(mx, 4)); mx = fmaxf(mx, __shfl_xor(mx, 8));
#pragma unroll
    for (int i = 0; i < 32; ++i) { p[i] = __expf(p[i] - mx); l += p[i]; }
    l += __shfl_xor(l, 1); l += __shfl_xor(l, 2);
    l += __shfl_xor(l, 4); l += __shfl_xor(l, 8);
  }
  const float invl = 1.0f / l;
  {
    const float* vxp = vxm + b * TS;
    const float* xp  = xin + (size_t)b * 3 * TS;
    float wsum = 0.f, xa0 = 0.f, xa1 = 0.f, xa2 = 0.f;
#pragma unroll
    for (int i = 0; i < 8; ++i) {
      int s = i * 64 + tx * 4;
      float4 vv = *(const float4*)(vxp + s);
      float4 x0 = *(const float4*)(xp + s);
      float4 x1 = *(const float4*)(xp + TS + s);
      float4 x2 = *(const float4*)(xp + 2 * TS + s);
      float wv;
      wv = p[4*i+0] * vv.x; wsum += wv; xa0 = fmaf(wv, x0.x, xa0); xa1 = fmaf(wv, x1.x, xa1); xa2 = fmaf(wv, x2.x, xa2);
      wv = p[4*i+1] * vv.y; wsum += wv; xa0 = fmaf(wv, x0.y, xa0); xa1 = fmaf(wv, x1.y, xa1); xa2 = fmaf(wv, x2.y, xa2);
      wv = p[4*i+2] * vv.z; wsum += wv; xa0 = fmaf(wv, x0.z, xa0); xa1 = fmaf(wv, x1.z, xa1); xa2 = fmaf(wv, x2.z, xa2);
      wv = p[4*i+3] * vv.w; wsum += wv; xa0 = fmaf(wv, x0.w, xa0); xa1 = fmaf(wv, x1.w, xa1); xa2 = fmaf(wv, x2.w, xa2);
    }
    wsum += __shfl_xor(wsum, 1); wsum += __shfl_xor(wsum, 2);
    wsum += __shfl_xor(wsum, 4); wsum += __shfl_xor(wsum, 8);
    xa0 += __shfl_xor(xa0, 1); xa0 += __shfl_xor(xa0, 2); xa0 += __shfl_xor(xa0, 4); xa0 += __shfl_xor(xa0, 8);
    xa1 += __shfl_xor(xa1, 1); xa1 += __shfl_xor(xa1, 2); xa1 += __shfl_xor(xa1, 4); xa1 += __shfl_xor(xa1, 8);
    xa2 += __shfl_xor(xa2, 1); xa2 += __shfl_xor(xa2, 2); xa2 += __shfl_xor(xa2, 4); xa2 += __shfl_xor(xa2, 8);
    if (tx == 0) {
      int t = t0 + row;
      float ws = wsum * invl;
      xout[(b * 3 + 0) * TS + t] = xp[t]           * (1.0f + ws) - xa0 * invl;
      xout[(b * 3 + 1) * TS + t] = xp[TS + t]      * (1.0f + ws) - xa1 * invl;
      xout[(b * 3 + 2) * TS + t] = xp[2 * TS + t]  * (1.0f + ws) - xa2 * invl;
      sml[row] = invl;
    }
  }
  __syncthreads();   // B2: everyone done reading S -> Pb/Pe may overwrite

  // ---- zero Pe (17408 B = 4352 words, 17/thread) ----
  {
    unsigned int* pz = (unsigned int*)Pe;
#pragma unroll
    for (int i = 0; i < 17; ++i) pz[i * 256 + tid] = 0u;
  }
  __syncthreads();   // B2b: Pe zeroed before scatter

  // ---- scatter P -> Pb (row-major) and Pe (banded: r_local = row+511-s) ----
  {
    unsigned short* pbrow = Pb + row * 520 + tx * 4;
    unsigned short* perow = Pe + row * 544 + row + 511;
#pragma unroll
    for (int i = 0; i < 8; ++i) {
      int s = i * 64 + tx * 4;
      ushort4 pu;
      pu.x = f2b(p[4*i+0]); pu.y = f2b(p[4*i+1]);
      pu.z = f2b(p[4*i+2]); pu.w = f2b(p[4*i+3]);
      *(ushort4*)(pbrow + i * 64) = pu;
      perow[-(s + 0)] = pu.x; perow[-(s + 1)] = pu.y;
      perow[-(s + 2)] = pu.z; perow[-(s + 3)] = pu.w;
    }
  }
  __syncthreads();   // B3: Pb/Pe/sml ready

  // ---- phase 2: O[t'][h] = P@Vt + Pe@embT-band, h-slice per wave ----
  const int n0 = w * 64;
  f32x4 oacc[4];
#pragma unroll
  for (int ni = 0; ni < 4; ++ni) oacc[ni] = (f32x4){0.f, 0.f, 0.f, 0.f};
  {
    const unsigned short* pbp = Pb + rq * 520 + kq * 8;
    const unsigned short* vtp = vtB + ((size_t)(b * 256 + n0 + rq) << 9) + kq * 8;
#pragma unroll
    for (int ks = 0; ks < 16; ++ks) {
      bf16x8 pa = *(const bf16x8*)(pbp + ks * 32);
      bf16x8 vf[4];
#pragma unroll
      for (int ni = 0; ni < 4; ++ni) vf[ni] = *(const bf16x8*)(vtp + ni * 8192 + ks * 32);
#pragma unroll
      for (int ni = 0; ni < 4; ++ni)
        oacc[ni] = __builtin_amdgcn_mfma_f32_16x16x32_bf16(pa, vf[ni], oacc[ni], 0, 0, 0);
    }
  }
  {
    const unsigned short* pep = Pe + rq * 544 + kq * 8;
    const unsigned short* etp = embT + ((size_t)(n0 + rq) << 10);
#pragma unroll
    for (int ks = 0; ks < 17; ++ks) {
      bf16x8 pa = *(const bf16x8*)(pep + ks * 32);
      int rg = t0 + ks * 32 + kq * 8;            // r_global = t0 + r_local
      if (rg > 1016) rg = 1016;                  // clamp only where Pe is zero
      bf16x8 ef[4];
#pragma unroll
      for (int ni = 0; ni < 4; ++ni) ef[ni] = *(const bf16x8*)(etp + (ni << 14) + rg);
#pragma unroll
      for (int ni = 0; ni < 4; ++ni)
        oacc[ni] = __builtin_amdgcn_mfma_f32_16x16x32_bf16(pa, ef[ni], oacc[ni], 0, 0, 0);
    }
  }

  // ---- epilogue: normalize by 1/l, add h residual, coalesced float4 ----
  {
    float il0 = sml[kq * 4 + 0], il1 = sml[kq * 4 + 1];
    float il2 = sml[kq * 4 + 2], il3 = sml[kq * 4 + 3];
#pragma unroll
    for (int ni = 0; ni < 4; ++ni) {
      int hh = n0 + ni * 16 + rq;
      size_t off = (((size_t)(b * 256 + hh)) << 9) + t0 + kq * 4;
      float4 hv = *(const float4*)(hin + off);
      float4 ov;
      ov.x = hv.x + oacc[ni][0] * il0;
      ov.y = hv.y + oacc[ni][1] * il1;
      ov.z = hv.z + oacc[ni][2] * il2;
      ov.w = hv.w + oacc[ni][3] * il3;
      *(float4*)(hout + off) = ov;
    }
  }
}

// ---------------------------------------------------------------------------
extern "C" void kernel_launch(void* const* d_in, const int* in_sizes, int n_in,
                              void* d_out, int out_size, void* d_ws, size_t ws_size,
                              hipStream_t stream)
{
  const float* x   = (const float*)d_in[0];
  const float* h   = (const float*)d_in[1];
  const float* qW1 = (const float*)d_in[2];
  const float* qb1 = (const float*)d_in[3];
  const float* qW2 = (const float*)d_in[4];
  const float* qb2 = (const float*)d_in[5];
  const float* kW1 = (const float*)d_in[6];
  const float* kb1 = (const float*)d_in[7];
  const float* kW2 = (const float*)d_in[8];
  const float* kb2 = (const float*)d_in[9];
  const float* vW1 = (const float*)d_in[10];
  const float* vb1 = (const float*)d_in[11];
  const float* vW2 = (const float*)d_in[12];
  const float* vb2 = (const float*)d_in[13];
  const float* xW1 = (const float*)d_in[14];
  const float* xb1 = (const float*)d_in[15];
  const float* xW2 = (const float*)d_in[16];
  const float* xb2 = (const float*)d_in[17];
  const float* teW = (const float*)d_in[18];
  const float* teb = (const float*)d_in[19];

  // ws layout (bf16 except vx) ~116 MB; hidV aliases hidQ, hidX aliases hidK
  unsigned short* cur = (unsigned short*)d_ws;
  unsigned short* embB  = cur; cur += 1023 * 256;
  unsigned short* embLo = cur; cur += 1023 * 256;
  unsigned short* embT  = cur; cur += 256 * 1024;
  unsigned short* hmB   = cur; cur += (size_t)24576 * 256;
  unsigned short* WtB   = cur; cur += 7 * 65536;
  unsigned short* hidQ  = cur; cur += (size_t)24576 * 256;
  unsigned short* hidK  = cur; cur += (size_t)24576 * 256;
  unsigned short* qBp   = cur; cur += (size_t)24576 * 256;
  unsigned short* qLo   = cur; cur += (size_t)24576 * 256;
  unsigned short* kBp   = cur; cur += (size_t)24576 * 256;
  unsigned short* kLo   = cur; cur += (size_t)24576 * 256;
  unsigned short* vBp   = cur; cur += (size_t)24576 * 256;
  unsigned short* vtB   = cur; cur += (size_t)24576 * 256;
  float* vx = (float*)cur;                                // 24576 f32
  unsigned short* hidV = hidQ;   // dead after L2-q/k launch
  unsigned short* hidX = hidK;   // dead after L2-q/k launch

  float* xout = (float*)d_out;                // [48,3,512]
  float* hout = xout + NB * 3 * TS;           // [48,256,512]

  k_embrel<<<1023, 256, 0, stream>>>(teW, teb, embB, embLo, embT);
  k_prep_h<<<dim3(4, 8, 48), 256, 0, stream>>>(h, hmB);
  k_prep_w<<<dim3(4, 4, 7), 256, 0, stream>>>(qW1, qW2, kW1, kW2, vW1, vW2, xW1, WtB);

  // q,k layer 1 (fused launch), then layer 2 (fused, with lo residuals)
  {
    GJobs j1{{{hmB, WtB + 0 * 65536, qb1, hidQ, nullptr},
              {hmB, WtB + 2 * 65536, kb1, hidK, nullptr}}};
    k_gemm<1><<<dim3(192, 2, 2), 256, 0, stream>>>(j1);
    GJobs j2{{{hidQ, WtB + 1 * 65536, qb2, qBp, qLo},
              {hidK, WtB + 3 * 65536, kb2, kBp, kLo}}};
    k_gemm<0><<<dim3(192, 2, 2), 256, 0, stream>>>(j2);
  }
  // v MLP (hidV reuses hidQ), then x-MLP layer 1 (hidX reuses hidK)
  {
    GJobs j3{{{hmB, WtB + 4 * 65536, vb1, hidV, nullptr}, {}}};
    k_gemm<1><<<dim3(192, 2, 1), 256, 0, stream>>>(j3);
    GJobs j4{{{hidV, WtB + 5 * 65536, vb2, vBp, nullptr}, {}}};
    k_gemm<0><<<dim3(192, 2, 1), 256, 0, stream>>>(j4);
    GJobs j5{{{vBp, WtB + 6 * 65536, xb1, hidX, nullptr}, {}}};
    k_gemm<1><<<dim3(192, 2, 1), 256, 0, stream>>>(j5);
  }
  k_vx2<<<768, 256, 0, stream>>>(hidX, xW2, xb2, vx);
  k_prep_vt<<<dim3(8, 4, 48), 256, 0, stream>>>(vBp, vtB);

  k_attn3<<<1536, 256, 0, stream>>>(x, h, qBp, qLo, kBp, kLo, vtB, vx,
                                    embB, embLo, embT, xout, hout);
}

// Round 7
// 299.760 us; speedup vs baseline: 1.6277x; 1.3992x over previous
//
#include <hip/hip_runtime.h>
#include <math.h>

// Problem constants
#define NB 48      // batch*nodes
#define HD 256     // hidden
#define TS 512     // timesteps
// 2T-1 = 1023 relative positions

typedef _Float16 f16x8 __attribute__((ext_vector_type(8)));
typedef float    f32x4 __attribute__((ext_vector_type(4)));

__device__ inline unsigned short f2h(float f) {       // f32 -> fp16 bits (RNE)
  union { _Float16 h; unsigned short u; } v; v.h = (_Float16)f; return v.u;
}
__device__ inline float h2f(unsigned short u) {
  union { unsigned short u; _Float16 h; } v; v.u = u; return (float)v.h;
}

// ---------------------------------------------------------------------------
// emb_rel[r][c] fp16: row-major [1023][256] AND transposed [256][1024] (pad 0)
// ---------------------------------------------------------------------------
__global__ __launch_bounds__(256) void k_embrel(
    const float* __restrict__ teW, const float* __restrict__ teb,
    unsigned short* __restrict__ embB, unsigned short* __restrict__ embT)
{
  __shared__ float e[256];
  const int r = blockIdx.x;        // 0..1022
  const int tid = threadIdx.x;
  const float rel = (float)(r - (TS - 1));
  if (tid < 128) {
    float f = expf((float)tid * (-9.210340371976184f / 127.0f)); // -ln(1e4)/(half-1)
    float ang = rel * f;
    e[tid] = sinf(ang);
    e[tid + 128] = cosf(ang);
  }
  __syncthreads();
  float acc = teb[tid];
  for (int kk = 0; kk < 256; ++kk)
    acc = fmaf(e[kk], teW[kk * 256 + tid], acc);
  unsigned short hv = f2h(acc);
  embB[r * 256 + tid] = hv;
  embT[(size_t)tid * 1024 + r] = hv;
  if (r == 0) embT[(size_t)tid * 1024 + 1023] = 0;  // pad col: keep finite
}

// ---------------------------------------------------------------------------
// h [48,256,512] fp32  ->  hmH [24576][256] fp16   (hm[m,c] = h[b,c,t])
// ---------------------------------------------------------------------------
__global__ __launch_bounds__(256) void k_prep_h(
    const float* __restrict__ h, unsigned short* __restrict__ hmH)
{
  __shared__ float t[32 * 132];
  const int t0 = blockIdx.x * 128, c0 = blockIdx.y * 32, b = blockIdx.z;
  const int tid = threadIdx.x;
#pragma unroll
  for (int i = 0; i < 4; ++i) {
    int cl = i * 8 + (tid >> 5);           // 0..31
    int t4 = (tid & 31) * 4;               // 0..124
    float4 v = *(const float4*)&h[((size_t)b * 256 + c0 + cl) * 512 + t0 + t4];
    t[cl * 132 + t4 + 0] = v.x; t[cl * 132 + t4 + 1] = v.y;
    t[cl * 132 + t4 + 2] = v.z; t[cl * 132 + t4 + 3] = v.w;
  }
  __syncthreads();
#pragma unroll
  for (int i = 0; i < 16; ++i) {
    int tl = i * 8 + (tid >> 5);           // 0..127
    int cl = tid & 31;
    hmH[((size_t)b * 512 + t0 + tl) * 256 + c0 + cl] = f2h(t[cl * 132 + tl]);
  }
}

// ---------------------------------------------------------------------------
// Weights fp32 [K=256][N=256] -> fp16 transposed [N][K], 7 matrices
// ---------------------------------------------------------------------------
__global__ __launch_bounds__(256) void k_prep_w(
    const float* __restrict__ w0, const float* __restrict__ w1,
    const float* __restrict__ w2, const float* __restrict__ w3,
    const float* __restrict__ w4, const float* __restrict__ w5,
    const float* __restrict__ w6, unsigned short* __restrict__ WtH)
{
  __shared__ float t[64 * 68];
  const int mat = blockIdx.z;
  const float* W = (mat == 0) ? w0 : (mat == 1) ? w1 : (mat == 2) ? w2 :
                   (mat == 3) ? w3 : (mat == 4) ? w4 : (mat == 5) ? w5 : w6;
  unsigned short* dst = WtH + (size_t)mat * 65536;
  const int k0 = blockIdx.x * 64, n0 = blockIdx.y * 64;
  const int tid = threadIdx.x;
#pragma unroll
  for (int i = 0; i < 4; ++i) {
    int kr = i * 16 + (tid >> 4);          // 0..63 local k
    int nc = (tid & 15) * 4;               // 0..60 local n
    float4 v = *(const float4*)&W[(size_t)(k0 + kr) * 256 + n0 + nc];
    t[kr * 68 + nc + 0] = v.x; t[kr * 68 + nc + 1] = v.y;
    t[kr * 68 + nc + 2] = v.z; t[kr * 68 + nc + 3] = v.w;
  }
  __syncthreads();
#pragma unroll
  for (int i = 0; i < 4; ++i) {
    int nr = i * 16 + (tid >> 4);          // local n
    int kc = (tid & 15) * 4;               // local k
#pragma unroll
    for (int j = 0; j < 4; ++j)
      dst[(size_t)(n0 + nr) * 256 + k0 + kc + j] = f2h(t[(kc + j) * 68 + nr]);
  }
}

// ---------------------------------------------------------------------------
// V fp16 [24576][256] -> Vt fp16 [48][256][512]  (dtype-agnostic shuffle)
// ---------------------------------------------------------------------------
__global__ __launch_bounds__(256) void k_prep_vt(
    const unsigned short* __restrict__ vH, unsigned short* __restrict__ vtH)
{
  __shared__ unsigned short tt[64][68];
  const int s0 = blockIdx.x * 64, h0 = blockIdx.y * 64, b = blockIdx.z;
  const int tid = threadIdx.x;
#pragma unroll
  for (int i = 0; i < 4; ++i) {
    int r = i * 16 + (tid >> 4);
    int c = (tid & 15) * 4;
    ushort4 v = *(const ushort4*)&vH[((size_t)(b * 512 + s0 + r) << 8) + h0 + c];
    tt[r][c + 0] = v.x; tt[r][c + 1] = v.y; tt[r][c + 2] = v.z; tt[r][c + 3] = v.w;
  }
  __syncthreads();
#pragma unroll
  for (int i = 0; i < 4; ++i) {
    int hr = i * 16 + (tid >> 4);
    int sc = (tid & 15) * 4;
    ushort4 o;
    o.x = tt[sc + 0][hr]; o.y = tt[sc + 1][hr];
    o.z = tt[sc + 2][hr]; o.w = tt[sc + 3][hr];
    *(ushort4*)&vtH[((size_t)(b * 256 + h0 + hr) << 9) + s0 + sc] = o;
  }
}

// ---------------------------------------------------------------------------
// fp16 MFMA GEMM, up-to-3-job batched via blockIdx.z:
//   C[M,256] = act(A[M,256] @ Wt^T + bias), fp16 out, f32 accumulate
// ---------------------------------------------------------------------------
struct GJob {
  const unsigned short* A; const unsigned short* Wt; const float* bias;
  unsigned short* outB;
};
struct GJobs { GJob j[3]; };

template<int ACT>
__global__ __launch_bounds__(256) void k_gemm(GJobs jobs)
{
  __shared__ uint4 As4[2048];   // 32 KB
  __shared__ uint4 Ws4[2048];   // 32 KB
  char* AsB = (char*)As4;
  char* WsB = (char*)Ws4;

  const GJob jb = jobs.j[blockIdx.z];

  const int tid  = threadIdx.x;
  const int lane = tid & 63;
  const int w    = tid >> 6;
  const int wr   = w >> 1, wc = w & 1;
  const int rq   = lane & 15;
  const int kq   = lane >> 4;

  const int m0 = blockIdx.x * 128;
  const int n0 = blockIdx.y * 128;
  const char* Ag = (const char*)jb.A  + (size_t)m0 * 512;
  const char* Wg = (const char*)jb.Wt + (size_t)n0 * 512;

  f32x4 acc[4][4];
#pragma unroll
  for (int mi = 0; mi < 4; ++mi)
#pragma unroll
    for (int ni = 0; ni < 4; ++ni)
      acc[mi][ni] = (f32x4){0.f, 0.f, 0.f, 0.f};

  for (int kt = 0; kt < 2; ++kt) {
    __syncthreads();
#pragma unroll
    for (int i = 0; i < 8; ++i) {
      int c = i * 256 + tid;
      int row = c >> 4;
      int colb = (c & 15) * 16;
      int sw = colb ^ ((row & 7) << 4);
      *(uint4*)(AsB + row * 256 + sw) =
          *(const uint4*)(Ag + (size_t)row * 512 + kt * 256 + colb);
      *(uint4*)(WsB + row * 256 + sw) =
          *(const uint4*)(Wg + (size_t)row * 512 + kt * 256 + colb);
    }
    __syncthreads();

#pragma unroll
    for (int kk = 0; kk < 4; ++kk) {
      const int kb = kk * 64 + kq * 16;
      f16x8 af[4], bfr[4];
#pragma unroll
      for (int mi = 0; mi < 4; ++mi) {
        int row = wr * 64 + mi * 16 + rq;
        af[mi] = *(const f16x8*)(AsB + row * 256 + (kb ^ ((row & 7) << 4)));
      }
#pragma unroll
      for (int ni = 0; ni < 4; ++ni) {
        int row = wc * 64 + ni * 16 + rq;
        bfr[ni] = *(const f16x8*)(WsB + row * 256 + (kb ^ ((row & 7) << 4)));
      }
#pragma unroll
      for (int mi = 0; mi < 4; ++mi)
#pragma unroll
        for (int ni = 0; ni < 4; ++ni)
          acc[mi][ni] = __builtin_amdgcn_mfma_f32_16x16x32_f16(
              af[mi], bfr[ni], acc[mi][ni], 0, 0, 0);
    }
  }

  float bv[4];
#pragma unroll
  for (int ni = 0; ni < 4; ++ni)
    bv[ni] = jb.bias[n0 + wc * 64 + ni * 16 + rq];

#pragma unroll
  for (int mi = 0; mi < 4; ++mi) {
#pragma unroll
    for (int ni = 0; ni < 4; ++ni) {
      const int n = n0 + wc * 64 + ni * 16 + rq;
#pragma unroll
      for (int j = 0; j < 4; ++j) {
        const int m = m0 + wr * 64 + mi * 16 + kq * 4 + j;
        float vl = acc[mi][ni][j] + bv[ni];
        if (ACT) vl = vl / (1.0f + __expf(-vl));
        jb.outB[(size_t)m * 256 + n] = f2h(vl);
      }
    }
  }
}

// ---------------------------------------------------------------------------
// vx[m] = hidX[m,:] (fp16) @ xW2 + xb2
// ---------------------------------------------------------------------------
__global__ __launch_bounds__(256) void k_vx2(
    const unsigned short* __restrict__ hid,
    const float* __restrict__ xW2, const float* __restrict__ xb2,
    float* __restrict__ vx)
{
  const int m0 = blockIdx.x * 32;
  const int tid = threadIdx.x;
  const int tr = tid >> 3, tc = tid & 7;
  const unsigned short* row = hid + (size_t)(m0 + tr) * 256 + tc * 32;
  float acc = 0.0f;
#pragma unroll
  for (int i = 0; i < 4; ++i) {
    uint4 r = *(const uint4*)&row[i * 8];
    const unsigned rr[4] = {r.x, r.y, r.z, r.w};
#pragma unroll
    for (int jj = 0; jj < 4; ++jj) {
      float lo = h2f((unsigned short)(rr[jj] & 0xffff));
      float hi = h2f((unsigned short)(rr[jj] >> 16));
      acc = fmaf(lo, xW2[tc * 32 + i * 8 + 2 * jj + 0], acc);
      acc = fmaf(hi, xW2[tc * 32 + i * 8 + 2 * jj + 1], acc);
    }
  }
  acc += __shfl_xor(acc, 1);
  acc += __shfl_xor(acc, 2);
  acc += __shfl_xor(acc, 4);
  if (tc == 0) vx[m0 + tr] = acc + xb2[0];
}

// ---------------------------------------------------------------------------
// MFMA fused attention, fp16 single-term, 34 KB LDS. Block = (b, 16 t-rows).
//  phase1: S = Q@K^T + band(Q@emb^T), accumulated directly in S.
//  softmax fp32 in regs (+ x-update); Pb/Pe ALIAS S.
//  phase2: O = P@Vt + Pe@embT-band.
// Grid 1D 1536, XCD-swizzled: all 32 t-tiles of one b on one XCD (id%8).
// LDS: S[16][524]f32 (33536 B)  UNION  { Pb[16][520] | Pe[16][544] } (34048 B)
//      sml[16] at +34048.  Total 34112 B.
// ---------------------------------------------------------------------------
__global__ __launch_bounds__(256, 2) void k_attn3(
    const float* __restrict__ xin, const float* __restrict__ hin,
    const unsigned short* __restrict__ qH, const unsigned short* __restrict__ kH,
    const unsigned short* __restrict__ vtH, const float* __restrict__ vxm,
    const unsigned short* __restrict__ embB, const unsigned short* __restrict__ embT,
    float* __restrict__ xout, float* __restrict__ hout)
{
  __shared__ char smem[34112];
  float* S  = (float*)smem;                              // [16][524]
  unsigned short* Pb = (unsigned short*)smem;            // [16][520], after S dies
  unsigned short* Pe = (unsigned short*)(smem + 16640);  // [16][544]
  float* sml = (float*)(smem + 34048);                   // [16]

  const int tid  = threadIdx.x;
  const int lane = tid & 63;
  const int w    = tid >> 6;
  const int rq   = lane & 15;
  const int kq   = lane >> 4;
  // XCD swizzle: id = xcd + 8*(bx + 32*bgrp); b = xcd + 8*bgrp, t0 = bx*16
  const int id = blockIdx.x;
  const int t0 = ((id >> 3) & 31) * 16;
  const int b  = (id & 7) + 8 * (id >> 8);
  const int sw = w * 128;          // this wave's s-offset (phase 1)

  // ---- Q fragments (held through phase 1) ----
  f16x8 qf[8];
  {
    const size_t qoff = ((size_t)(b * TS + t0 + rq) << 8) + kq * 8;
#pragma unroll
    for (int ks = 0; ks < 8; ++ks)
      qf[ks] = *(const f16x8*)(qH + qoff + ks * 32);
  }

  // ---- phase 1a: QK^T for s in [sw, sw+128) ----
  {
    f32x4 acc[8];
#pragma unroll
    for (int ni = 0; ni < 8; ++ni) acc[ni] = (f32x4){0.f, 0.f, 0.f, 0.f};
    const unsigned short* kp = kH + ((size_t)(b * TS + sw + rq) << 8) + kq * 8;
#pragma unroll
    for (int ks = 0; ks < 8; ++ks) {
#pragma unroll
      for (int ni = 0; ni < 8; ++ni) {
        f16x8 kf = *(const f16x8*)(kp + ni * 4096 + ks * 32);
        acc[ni] = __builtin_amdgcn_mfma_f32_16x16x32_f16(qf[ks], kf, acc[ni], 0, 0, 0);
      }
    }
    // flush acc -> S (final values): frees regs before racc goes live
#pragma unroll
    for (int ni = 0; ni < 8; ++ni)
#pragma unroll
      for (int j = 0; j < 4; ++j)
        S[(kq * 4 + j) * 524 + sw + ni * 16 + rq] = acc[ni][j];
  }

  // ---- phase 1b: racc[t'][r_local] = Q . embband^T (143-wide band, 9 frags)
  f32x4 racc[9];
#pragma unroll
  for (int ni = 0; ni < 9; ++ni) racc[ni] = (f32x4){0.f, 0.f, 0.f, 0.f};
  const int rbR = t0 - sw + 384;            // r_global = rbR + r_local
  {
    const unsigned short* ep[9];
#pragma unroll
    for (int ni = 0; ni < 9; ++ni) {
      int rr = rbR + ni * 16 + rq;
      if (rr > 1022) rr = 1022;             // only r_local=143 (never gathered)
      ep[ni] = embB + ((size_t)rr << 8) + kq * 8;
    }
#pragma unroll
    for (int ks = 0; ks < 8; ++ks) {
#pragma unroll
      for (int ni = 0; ni < 9; ++ni) {
        f16x8 ef = *(const f16x8*)(ep[ni] + ks * 32);
        racc[ni] = __builtin_amdgcn_mfma_f32_16x16x32_f16(qf[ks], ef, racc[ni], 0, 0, 0);
      }
    }
  }

  // ---- fence, then RMW racc into S ----
  // slot (tp, slw): acc element (ni=slw>>4, rq=slw&15, j=tp&3, kq=tp>>2);
  // racc element for it: r_local = tp+127-slw  ->  (ni=r_local>>4, rq=r_local&15).
  // Both bijective -> each slot written once, RMW'd by exactly one lane.
  asm volatile("s_waitcnt lgkmcnt(0)" ::: "memory");  // same-wave LDS visibility
  __builtin_amdgcn_sched_barrier(0);                  // rule #18: pin the fence
#pragma unroll
  for (int ni = 0; ni < 9; ++ni)
#pragma unroll
    for (int j = 0; j < 4; ++j) {
      int tp  = kq * 4 + j;
      int slw = tp + 127 - (ni * 16 + rq);  // s-window slot this element feeds
      if (slw >= 0 && slw < 128)
        S[tp * 524 + sw + slw] += racc[ni][j];
    }
  __syncthreads();   // B1: S complete across waves

  // ---- softmax (16 threads per row) + x-update ----
  const int row = tid >> 4, tx = tid & 15;
  float p[32];
  float mx = -3.0e38f, l = 0.f;
  {
    const float* Srow = S + row * 524 + tx * 4;
#pragma unroll
    for (int i = 0; i < 8; ++i) {
      float4 v = *(const float4*)(Srow + i * 64);
      p[4*i+0] = v.x; p[4*i+1] = v.y; p[4*i+2] = v.z; p[4*i+3] = v.w;
    }
#pragma unroll
    for (int i = 0; i < 32; ++i) mx = fmaxf(mx, p[i]);
    mx = fmaxf(mx, __shfl_xor(mx, 1)); mx = fmaxf(mx, __shfl_xor(mx, 2));
    mx = fmaxf(mx, __shfl_xor(mx, 4)); mx = fmaxf(mx, __shfl_xor(mx, 8));
#pragma unroll
    for (int i = 0; i < 32; ++i) { p[i] = __expf(p[i] - mx); l += p[i]; }
    l += __shfl_xor(l, 1); l += __shfl_xor(l, 2);
    l += __shfl_xor(l, 4); l += __shfl_xor(l, 8);
  }
  const float invl = 1.0f / l;
  {
    const float* vxp = vxm + b * TS;
    const float* xp  = xin + (size_t)b * 3 * TS;
    float wsum = 0.f, xa0 = 0.f, xa1 = 0.f, xa2 = 0.f;
#pragma unroll
    for (int i = 0; i < 8; ++i) {
      int s = i * 64 + tx * 4;
      float4 vv = *(const float4*)(vxp + s);
      float4 x0 = *(const float4*)(xp + s);
      float4 x1 = *(const float4*)(xp + TS + s);
      float4 x2 = *(const float4*)(xp + 2 * TS + s);
      float wv;
      wv = p[4*i+0] * vv.x; wsum += wv; xa0 = fmaf(wv, x0.x, xa0); xa1 = fmaf(wv, x1.x, xa1); xa2 = fmaf(wv, x2.x, xa2);
      wv = p[4*i+1] * vv.y; wsum += wv; xa0 = fmaf(wv, x0.y, xa0); xa1 = fmaf(wv, x1.y, xa1); xa2 = fmaf(wv, x2.y, xa2);
      wv = p[4*i+2] * vv.z; wsum += wv; xa0 = fmaf(wv, x0.z, xa0); xa1 = fmaf(wv, x1.z, xa1); xa2 = fmaf(wv, x2.z, xa2);
      wv = p[4*i+3] * vv.w; wsum += wv; xa0 = fmaf(wv, x0.w, xa0); xa1 = fmaf(wv, x1.w, xa1); xa2 = fmaf(wv, x2.w, xa2);
    }
    wsum += __shfl_xor(wsum, 1); wsum += __shfl_xor(wsum, 2);
    wsum += __shfl_xor(wsum, 4); wsum += __shfl_xor(wsum, 8);
    xa0 += __shfl_xor(xa0, 1); xa0 += __shfl_xor(xa0, 2); xa0 += __shfl_xor(xa0, 4); xa0 += __shfl_xor(xa0, 8);
    xa1 += __shfl_xor(xa1, 1); xa1 += __shfl_xor(xa1, 2); xa1 += __shfl_xor(xa1, 4); xa1 += __shfl_xor(xa1, 8);
    xa2 += __shfl_xor(xa2, 1); xa2 += __shfl_xor(xa2, 2); xa2 += __shfl_xor(xa2, 4); xa2 += __shfl_xor(xa2, 8);
    if (tx == 0) {
      int t = t0 + row;
      float ws = wsum * invl;
      xout[(b * 3 + 0) * TS + t] = xp[t]           * (1.0f + ws) - xa0 * invl;
      xout[(b * 3 + 1) * TS + t] = xp[TS + t]      * (1.0f + ws) - xa1 * invl;
      xout[(b * 3 + 2) * TS + t] = xp[2 * TS + t]  * (1.0f + ws) - xa2 * invl;
      sml[row] = invl;
    }
  }
  __syncthreads();   // B2: everyone done reading S -> Pb/Pe may overwrite

  // ---- zero Pe (17408 B = 4352 words, 17/thread) ----
  {
    unsigned int* pz = (unsigned int*)Pe;
#pragma unroll
    for (int i = 0; i < 17; ++i) pz[i * 256 + tid] = 0u;
  }
  __syncthreads();   // B2b: Pe zeroed before scatter

  // ---- scatter P -> Pb (row-major) and Pe (banded: r_local = row+511-s) ----
  {
    unsigned short* pbrow = Pb + row * 520 + tx * 4;
    unsigned short* perow = Pe + row * 544 + row + 511;
#pragma unroll
    for (int i = 0; i < 8; ++i) {
      int s = i * 64 + tx * 4;
      ushort4 pu;
      pu.x = f2h(p[4*i+0]); pu.y = f2h(p[4*i+1]);
      pu.z = f2h(p[4*i+2]); pu.w = f2h(p[4*i+3]);
      *(ushort4*)(pbrow + i * 64) = pu;
      perow[-(s + 0)] = pu.x; perow[-(s + 1)] = pu.y;
      perow[-(s + 2)] = pu.z; perow[-(s + 3)] = pu.w;
    }
  }
  __syncthreads();   // B3: Pb/Pe/sml ready

  // ---- phase 2: O[t'][h] = P@Vt + Pe@embT-band, h-slice per wave ----
  const int n0 = w * 64;
  f32x4 oacc[4];
#pragma unroll
  for (int ni = 0; ni < 4; ++ni) oacc[ni] = (f32x4){0.f, 0.f, 0.f, 0.f};
  {
    const unsigned short* pbp = Pb + rq * 520 + kq * 8;
    const unsigned short* vtp = vtH + ((size_t)(b * 256 + n0 + rq) << 9) + kq * 8;
#pragma unroll
    for (int ks = 0; ks < 16; ++ks) {
      f16x8 pa = *(const f16x8*)(pbp + ks * 32);
      f16x8 vf[4];
#pragma unroll
      for (int ni = 0; ni < 4; ++ni) vf[ni] = *(const f16x8*)(vtp + ni * 8192 + ks * 32);
#pragma unroll
      for (int ni = 0; ni < 4; ++ni)
        oacc[ni] = __builtin_amdgcn_mfma_f32_16x16x32_f16(pa, vf[ni], oacc[ni], 0, 0, 0);
    }
  }
  {
    const unsigned short* pep = Pe + rq * 544 + kq * 8;
    const unsigned short* etp = embT + ((size_t)(n0 + rq) << 10);
#pragma unroll
    for (int ks = 0; ks < 17; ++ks) {
      f16x8 pa = *(const f16x8*)(pep + ks * 32);
      int rg = t0 + ks * 32 + kq * 8;            // r_global = t0 + r_local
      if (rg > 1016) rg = 1016;                  // clamp only where Pe is zero
      f16x8 ef[4];
#pragma unroll
      for (int ni = 0; ni < 4; ++ni) ef[ni] = *(const f16x8*)(etp + (ni << 14) + rg);
#pragma unroll
      for (int ni = 0; ni < 4; ++ni)
        oacc[ni] = __builtin_amdgcn_mfma_f32_16x16x32_f16(pa, ef[ni], oacc[ni], 0, 0, 0);
    }
  }

  // ---- epilogue: normalize by 1/l, add h residual, coalesced float4 ----
  {
    float il0 = sml[kq * 4 + 0], il1 = sml[kq * 4 + 1];
    float il2 = sml[kq * 4 + 2], il3 = sml[kq * 4 + 3];
#pragma unroll
    for (int ni = 0; ni < 4; ++ni) {
      int hh = n0 + ni * 16 + rq;
      size_t off = (((size_t)(b * 256 + hh)) << 9) + t0 + kq * 4;
      float4 hv = *(const float4*)(hin + off);
      float4 ov;
      ov.x = hv.x + oacc[ni][0] * il0;
      ov.y = hv.y + oacc[ni][1] * il1;
      ov.z = hv.z + oacc[ni][2] * il2;
      ov.w = hv.w + oacc[ni][3] * il3;
      *(float4*)(hout + off) = ov;
    }
  }
}

// ---------------------------------------------------------------------------
extern "C" void kernel_launch(void* const* d_in, const int* in_sizes, int n_in,
                              void* d_out, int out_size, void* d_ws, size_t ws_size,
                              hipStream_t stream)
{
  const float* x   = (const float*)d_in[0];
  const float* h   = (const float*)d_in[1];
  const float* qW1 = (const float*)d_in[2];
  const float* qb1 = (const float*)d_in[3];
  const float* qW2 = (const float*)d_in[4];
  const float* qb2 = (const float*)d_in[5];
  const float* kW1 = (const float*)d_in[6];
  const float* kb1 = (const float*)d_in[7];
  const float* kW2 = (const float*)d_in[8];
  const float* kb2 = (const float*)d_in[9];
  const float* vW1 = (const float*)d_in[10];
  const float* vb1 = (const float*)d_in[11];
  const float* vW2 = (const float*)d_in[12];
  const float* vb2 = (const float*)d_in[13];
  const float* xW1 = (const float*)d_in[14];
  const float* xb1 = (const float*)d_in[15];
  const float* xW2 = (const float*)d_in[16];
  const float* xb2 = (const float*)d_in[17];
  const float* teW = (const float*)d_in[18];
  const float* teb = (const float*)d_in[19];

  // ws layout (fp16 except vx) ~103 MB
  unsigned short* cur = (unsigned short*)d_ws;
  unsigned short* embB = cur; cur += 1023 * 256;
  unsigned short* embT = cur; cur += 256 * 1024;
  unsigned short* hmH  = cur; cur += (size_t)24576 * 256;
  unsigned short* WtH  = cur; cur += 7 * 65536;
  unsigned short* hidQ = cur; cur += (size_t)24576 * 256;
  unsigned short* hidK = cur; cur += (size_t)24576 * 256;
  unsigned short* hidV = cur; cur += (size_t)24576 * 256;
  unsigned short* qHp  = cur; cur += (size_t)24576 * 256;
  unsigned short* kHp  = cur; cur += (size_t)24576 * 256;
  unsigned short* vHp  = cur; cur += (size_t)24576 * 256;
  unsigned short* vtH  = cur; cur += (size_t)24576 * 256;
  float* vx = (float*)cur;                                // 24576 f32
  unsigned short* hidX = hidQ;   // dead after layer-2 launch

  float* xout = (float*)d_out;                // [48,3,512]
  float* hout = xout + NB * 3 * TS;           // [48,256,512]

  k_embrel<<<1023, 256, 0, stream>>>(teW, teb, embB, embT);
  k_prep_h<<<dim3(4, 8, 48), 256, 0, stream>>>(h, hmH);
  k_prep_w<<<dim3(4, 4, 7), 256, 0, stream>>>(qW1, qW2, kW1, kW2, vW1, vW2, xW1, WtH);

  // layer 1 (q,k,v in one launch), layer 2 (q,k,v in one launch)
  {
    GJobs j1{{{hmH, WtH + 0 * 65536, qb1, hidQ},
              {hmH, WtH + 2 * 65536, kb1, hidK},
              {hmH, WtH + 4 * 65536, vb1, hidV}}};
    k_gemm<1><<<dim3(192, 2, 3), 256, 0, stream>>>(j1);
    GJobs j2{{{hidQ, WtH + 1 * 65536, qb2, qHp},
              {hidK, WtH + 3 * 65536, kb2, kHp},
              {hidV, WtH + 5 * 65536, vb2, vHp}}};
    k_gemm<0><<<dim3(192, 2, 3), 256, 0, stream>>>(j2);
  }
  // x-MLP layer 1 (input = v; hidX reuses hidQ), then matvec layer 2
  {
    GJobs j3{{{vHp, WtH + 6 * 65536, xb1, hidX}, {}, {}}};
    k_gemm<1><<<dim3(192, 2, 1), 256, 0, stream>>>(j3);
  }
  k_vx2<<<768, 256, 0, stream>>>(hidX, xW2, xb2, vx);
  k_prep_vt<<<dim3(8, 4, 48), 256, 0, stream>>>(vHp, vtH);

  k_attn3<<<1536, 256, 0, stream>>>(x, h, qHp, kHp, vtH, vx,
                                    embB, embT, xout, hout);
}

// Round 8
// 276.223 us; speedup vs baseline: 1.7664x; 1.0852x over previous
//
#include <hip/hip_runtime.h>
#include <math.h>

// Problem constants
#define NB 48      // batch*nodes
#define HD 256     // hidden
#define TS 512     // timesteps
// 2T-1 = 1023 relative positions; embT padded to 1056 cols

typedef _Float16 f16x8 __attribute__((ext_vector_type(8)));
typedef float    f32x4 __attribute__((ext_vector_type(4)));

__device__ inline unsigned short f2h(float f) {       // f32 -> fp16 bits (RNE)
  union { _Float16 h; unsigned short u; } v; v.h = (_Float16)f; return v.u;
}
__device__ inline float h2f(unsigned short u) {
  union { unsigned short u; _Float16 h; } v; v.u = u; return (float)v.h;
}

#define ETS 1056   // embT row stride (cols 1023..1055 zero)

// ---------------------------------------------------------------------------
// emb_rel fp16: embB [1024][256] (row 1023 = 0), embT [256][1056] (pad = 0)
// ---------------------------------------------------------------------------
__global__ __launch_bounds__(256) void k_embrel(
    const float* __restrict__ teW, const float* __restrict__ teb,
    unsigned short* __restrict__ embB, unsigned short* __restrict__ embT)
{
  __shared__ float e[256];
  const int r = blockIdx.x;        // 0..1023
  const int tid = threadIdx.x;
  if (r == 1023) {                 // zero pads (block-uniform branch)
    embB[1023 * 256 + tid] = 0;
    for (int c = 1023; c < ETS; ++c) embT[(size_t)tid * ETS + c] = 0;
    return;
  }
  const float rel = (float)(r - (TS - 1));
  if (tid < 128) {
    float f = expf((float)tid * (-9.210340371976184f / 127.0f)); // -ln(1e4)/(half-1)
    float ang = rel * f;
    e[tid] = sinf(ang);
    e[tid + 128] = cosf(ang);
  }
  __syncthreads();
  float acc = teb[tid];
  for (int kk = 0; kk < 256; ++kk)
    acc = fmaf(e[kk], teW[kk * 256 + tid], acc);
  unsigned short hv = f2h(acc);
  embB[r * 256 + tid] = hv;
  embT[(size_t)tid * ETS + r] = hv;
}

// ---------------------------------------------------------------------------
// h [48,256,512] fp32 -> hmH [24576][256] fp16; also zeroes vx[24576]
// ---------------------------------------------------------------------------
__global__ __launch_bounds__(256) void k_prep_h(
    const float* __restrict__ h, unsigned short* __restrict__ hmH,
    float* __restrict__ vxZ)
{
  __shared__ float t[32 * 132];
  const int t0 = blockIdx.x * 128, c0 = blockIdx.y * 32, b = blockIdx.z;
  const int tid = threadIdx.x;
  if (blockIdx.y == 0 && blockIdx.z == 0) {        // zero vx (4 blocks x 256 x 24)
    float4* vz = (float4*)(vxZ + ((size_t)blockIdx.x * 256 + tid) * 24);
#pragma unroll
    for (int i = 0; i < 6; ++i) vz[i] = make_float4(0.f, 0.f, 0.f, 0.f);
  }
#pragma unroll
  for (int i = 0; i < 4; ++i) {
    int cl = i * 8 + (tid >> 5);           // 0..31
    int t4 = (tid & 31) * 4;               // 0..124
    float4 v = *(const float4*)&h[((size_t)b * 256 + c0 + cl) * 512 + t0 + t4];
    t[cl * 132 + t4 + 0] = v.x; t[cl * 132 + t4 + 1] = v.y;
    t[cl * 132 + t4 + 2] = v.z; t[cl * 132 + t4 + 3] = v.w;
  }
  __syncthreads();
#pragma unroll
  for (int i = 0; i < 16; ++i) {
    int tl = i * 8 + (tid >> 5);           // 0..127
    int cl = tid & 31;
    hmH[((size_t)b * 512 + t0 + tl) * 256 + c0 + cl] = f2h(t[cl * 132 + tl]);
  }
}

// ---------------------------------------------------------------------------
// Weights fp32 [K=256][N=256] -> fp16 transposed [N][K], 7 matrices
// ---------------------------------------------------------------------------
__global__ __launch_bounds__(256) void k_prep_w(
    const float* __restrict__ w0, const float* __restrict__ w1,
    const float* __restrict__ w2, const float* __restrict__ w3,
    const float* __restrict__ w4, const float* __restrict__ w5,
    const float* __restrict__ w6, unsigned short* __restrict__ WtH)
{
  __shared__ float t[64 * 68];
  const int mat = blockIdx.z;
  const float* W = (mat == 0) ? w0 : (mat == 1) ? w1 : (mat == 2) ? w2 :
                   (mat == 3) ? w3 : (mat == 4) ? w4 : (mat == 5) ? w5 : w6;
  unsigned short* dst = WtH + (size_t)mat * 65536;
  const int k0 = blockIdx.x * 64, n0 = blockIdx.y * 64;
  const int tid = threadIdx.x;
#pragma unroll
  for (int i = 0; i < 4; ++i) {
    int kr = i * 16 + (tid >> 4);          // 0..63 local k
    int nc = (tid & 15) * 4;               // 0..60 local n
    float4 v = *(const float4*)&W[(size_t)(k0 + kr) * 256 + n0 + nc];
    t[kr * 68 + nc + 0] = v.x; t[kr * 68 + nc + 1] = v.y;
    t[kr * 68 + nc + 2] = v.z; t[kr * 68 + nc + 3] = v.w;
  }
  __syncthreads();
#pragma unroll
  for (int i = 0; i < 4; ++i) {
    int nr = i * 16 + (tid >> 4);          // local n
    int kc = (tid & 15) * 4;               // local k
#pragma unroll
    for (int j = 0; j < 4; ++j)
      dst[(size_t)(n0 + nr) * 256 + k0 + kc + j] = f2h(t[(kc + j) * 68 + nr]);
  }
}

// ---------------------------------------------------------------------------
// fp16 MFMA GEMM, up-to-3-job batched via blockIdx.z.
//   C[M,256] = act(A @ Wt^T + bias)
//   outB: fp16 row-major (optional) | outT: fp16 transposed [b][n][t] (opt)
//   vxOut: fused matvec vx[m] += C[m,:].vxW (atomicAdd; vx pre-zeroed) (opt)
// ---------------------------------------------------------------------------
struct GJob {
  const unsigned short* A; const unsigned short* Wt; const float* bias;
  unsigned short* outB; unsigned short* outT;
  const float* vxW; float* vxOut;
};
struct GJobs { GJob j[3]; };

template<int ACT>
__global__ __launch_bounds__(256) void k_gemm(GJobs jobs)
{
  __shared__ uint4 As4[2048];   // 32 KB
  __shared__ uint4 Ws4[2048];   // 32 KB
  char* AsB = (char*)As4;
  char* WsB = (char*)Ws4;

  const GJob jb = jobs.j[blockIdx.z];

  const int tid  = threadIdx.x;
  const int lane = tid & 63;
  const int w    = tid >> 6;
  const int wr   = w >> 1, wc = w & 1;
  const int rq   = lane & 15;
  const int kq   = lane >> 4;

  const int m0 = blockIdx.x * 128;
  const int n0 = blockIdx.y * 128;
  const char* Ag = (const char*)jb.A  + (size_t)m0 * 512;
  const char* Wg = (const char*)jb.Wt + (size_t)n0 * 512;

  f32x4 acc[4][4];
#pragma unroll
  for (int mi = 0; mi < 4; ++mi)
#pragma unroll
    for (int ni = 0; ni < 4; ++ni)
      acc[mi][ni] = (f32x4){0.f, 0.f, 0.f, 0.f};

  for (int kt = 0; kt < 2; ++kt) {
    __syncthreads();
#pragma unroll
    for (int i = 0; i < 8; ++i) {
      int c = i * 256 + tid;
      int row = c >> 4;
      int colb = (c & 15) * 16;
      int sw = colb ^ ((row & 7) << 4);
      *(uint4*)(AsB + row * 256 + sw) =
          *(const uint4*)(Ag + (size_t)row * 512 + kt * 256 + colb);
      *(uint4*)(WsB + row * 256 + sw) =
          *(const uint4*)(Wg + (size_t)row * 512 + kt * 256 + colb);
    }
    __syncthreads();

#pragma unroll
    for (int kk = 0; kk < 4; ++kk) {
      const int kb = kk * 64 + kq * 16;
      f16x8 af[4], bfr[4];
#pragma unroll
      for (int mi = 0; mi < 4; ++mi) {
        int row = wr * 64 + mi * 16 + rq;
        af[mi] = *(const f16x8*)(AsB + row * 256 + (kb ^ ((row & 7) << 4)));
      }
#pragma unroll
      for (int ni = 0; ni < 4; ++ni) {
        int row = wc * 64 + ni * 16 + rq;
        bfr[ni] = *(const f16x8*)(WsB + row * 256 + (kb ^ ((row & 7) << 4)));
      }
#pragma unroll
      for (int mi = 0; mi < 4; ++mi)
#pragma unroll
        for (int ni = 0; ni < 4; ++ni)
          acc[mi][ni] = __builtin_amdgcn_mfma_f32_16x16x32_f16(
              af[mi], bfr[ni], acc[mi][ni], 0, 0, 0);
    }
  }

  float bv[4];
#pragma unroll
  for (int ni = 0; ni < 4; ++ni)
    bv[ni] = jb.bias[n0 + wc * 64 + ni * 16 + rq];

  float vxp_[4][4];             // per (mi, j) partial vx dot (if vxOut)
#pragma unroll
  for (int mi = 0; mi < 4; ++mi)
#pragma unroll
    for (int j = 0; j < 4; ++j) vxp_[mi][j] = 0.f;

  const int bb = m0 >> 9;                    // batch of this tile
  const int tbase = (m0 & 511) + wr * 64;    // local t base

#pragma unroll
  for (int mi = 0; mi < 4; ++mi) {
#pragma unroll
    for (int ni = 0; ni < 4; ++ni) {
      const int n = n0 + wc * 64 + ni * 16 + rq;
      float vl4[4];
#pragma unroll
      for (int j = 0; j < 4; ++j) {
        float vl = acc[mi][ni][j] + bv[ni];
        if (ACT) vl = vl / (1.0f + __expf(-vl));
        vl4[j] = vl;
      }
      if (jb.outB) {
        const int m = m0 + wr * 64 + mi * 16 + kq * 4;
#pragma unroll
        for (int j = 0; j < 4; ++j)
          jb.outB[(size_t)(m + j) * 256 + n] = f2h(vl4[j]);
      }
      if (jb.outT) {                         // transposed: [b][n][t], 4 t's
        ushort4 o;
        o.x = f2h(vl4[0]); o.y = f2h(vl4[1]);
        o.z = f2h(vl4[2]); o.w = f2h(vl4[3]);
        *(ushort4*)&jb.outT[((size_t)(bb * 256 + n) << 9) +
                            tbase + mi * 16 + kq * 4] = o;
      }
      if (jb.vxOut) {
        float wq = jb.vxW[n];
#pragma unroll
        for (int j = 0; j < 4; ++j) vxp_[mi][j] = fmaf(vl4[j], wq, vxp_[mi][j]);
      }
    }
  }

  if (jb.vxOut) {              // reduce over rq (16 lanes), atomicAdd per m
#pragma unroll
    for (int mi = 0; mi < 4; ++mi)
#pragma unroll
      for (int j = 0; j < 4; ++j) {
        float s = vxp_[mi][j];
        s += __shfl_xor(s, 1); s += __shfl_xor(s, 2);
        s += __shfl_xor(s, 4); s += __shfl_xor(s, 8);
        if (rq == 0)
          atomicAdd(&jb.vxOut[m0 + wr * 64 + mi * 16 + kq * 4 + j], s);
      }
  }
}

// ---------------------------------------------------------------------------
// MFMA fused attention, fp16, 34 KB LDS, software-pipelined loads.
//  phase1: S = Q@K^T + band(Q@emb^T)  (depth-2 named prefetch buffers)
//  softmax fp32 in regs (+ x-update); Pb/Pe alias S.
//  phase2: O = P@Vt + Pe@embT-band    (two interleaved prefetched streams)
// Grid 1D 1536, XCD-swizzled. LDS 34112 B.
// ---------------------------------------------------------------------------
__global__ __launch_bounds__(256, 2) void k_attn3(
    const float* __restrict__ xin, const float* __restrict__ hin,
    const unsigned short* __restrict__ qH, const unsigned short* __restrict__ kH,
    const unsigned short* __restrict__ vtH, const float* __restrict__ vxm,
    const float* __restrict__ xb2p,
    const unsigned short* __restrict__ embB, const unsigned short* __restrict__ embT,
    float* __restrict__ xout, float* __restrict__ hout)
{
  __shared__ char smem[34112];
  float* S  = (float*)smem;                              // [16][524]
  unsigned short* Pb = (unsigned short*)smem;            // [16][520], after S dies
  unsigned short* Pe = (unsigned short*)(smem + 16640);  // [16][544]
  float* sml = (float*)(smem + 34048);                   // [16]

  const int tid  = threadIdx.x;
  const int lane = tid & 63;
  const int w    = tid >> 6;
  const int rq   = lane & 15;
  const int kq   = lane >> 4;
  // XCD swizzle: id = xcd + 8*(bx + 32*bgrp); b = xcd + 8*bgrp, t0 = bx*16
  const int id = blockIdx.x;
  const int t0 = ((id >> 3) & 31) * 16;
  const int b  = (id & 7) + 8 * (id >> 8);
  const int sw = w * 128;          // this wave's s-offset (phase 1)

  // ---- Q fragments (held through phase 1) ----
  f16x8 qf[8];
  {
    const size_t qoff = ((size_t)(b * TS + t0 + rq) << 8) + kq * 8;
#pragma unroll
    for (int ks = 0; ks < 8; ++ks)
      qf[ks] = *(const f16x8*)(qH + qoff + ks * 32);
  }

  // ---- phase 1a: QK^T for s in [sw, sw+128), depth-2 pipelined ----
  f32x4 acc[8];
#pragma unroll
  for (int ni = 0; ni < 8; ++ni) acc[ni] = (f32x4){0.f, 0.f, 0.f, 0.f};
  {
    const unsigned short* kp = kH + ((size_t)(b * TS + sw + rq) << 8) + kq * 8;
    f16x8 kA[8], kB[8];
#pragma unroll
    for (int ni = 0; ni < 8; ++ni) kA[ni] = *(const f16x8*)(kp + ni * 4096);
#pragma unroll
    for (int ni = 0; ni < 8; ++ni) kB[ni] = *(const f16x8*)(kp + ni * 4096 + 32);
#pragma unroll
    for (int ks = 0; ks < 8; ks += 2) {
#pragma unroll
      for (int ni = 0; ni < 8; ++ni) {
        acc[ni] = __builtin_amdgcn_mfma_f32_16x16x32_f16(qf[ks], kA[ni], acc[ni], 0, 0, 0);
        if (ks + 2 < 8) kA[ni] = *(const f16x8*)(kp + ni * 4096 + (ks + 2) * 32);
      }
#pragma unroll
      for (int ni = 0; ni < 8; ++ni) {
        acc[ni] = __builtin_amdgcn_mfma_f32_16x16x32_f16(qf[ks + 1], kB[ni], acc[ni], 0, 0, 0);
        if (ks + 3 < 8) kB[ni] = *(const f16x8*)(kp + ni * 4096 + (ks + 3) * 32);
      }
    }
  }

  // ---- issue phase-1b first loads, then flush acc -> S (frees acc regs) ----
  const int rbR = t0 - sw + 384;            // band base; row 1023 is zeros
  const unsigned short* ep = embB + ((size_t)(rbR + rq) << 8) + kq * 8;
  f16x8 eA[9], eB[9];
#pragma unroll
  for (int ni = 0; ni < 9; ++ni) eA[ni] = *(const f16x8*)(ep + ni * 4096);
#pragma unroll
  for (int ni = 0; ni < 8; ++ni)
#pragma unroll
    for (int j = 0; j < 4; ++j)
      S[(kq * 4 + j) * 524 + sw + ni * 16 + rq] = acc[ni][j];
#pragma unroll
  for (int ni = 0; ni < 9; ++ni) eB[ni] = *(const f16x8*)(ep + ni * 4096 + 32);

  // ---- phase 1b: racc = Q . embband^T (9 frags), depth-2 pipelined ----
  f32x4 racc[9];
#pragma unroll
  for (int ni = 0; ni < 9; ++ni) racc[ni] = (f32x4){0.f, 0.f, 0.f, 0.f};
#pragma unroll
  for (int ks = 0; ks < 8; ks += 2) {
#pragma unroll
    for (int ni = 0; ni < 9; ++ni) {
      racc[ni] = __builtin_amdgcn_mfma_f32_16x16x32_f16(qf[ks], eA[ni], racc[ni], 0, 0, 0);
      if (ks + 2 < 8) eA[ni] = *(const f16x8*)(ep + ni * 4096 + (ks + 2) * 32);
    }
#pragma unroll
    for (int ni = 0; ni < 9; ++ni) {
      racc[ni] = __builtin_amdgcn_mfma_f32_16x16x32_f16(qf[ks + 1], eB[ni], racc[ni], 0, 0, 0);
      if (ks + 3 < 8) eB[ni] = *(const f16x8*)(ep + ni * 4096 + (ks + 3) * 32);
    }
  }

  // ---- fence, then RMW racc into S ----
  // slot (tp, slw): acc element (ni=slw>>4, rq=slw&15, j=tp&3, kq=tp>>2);
  // racc element: r_local = tp+127-slw -> (ni=r_local>>4, rq=r_local&15).
  // Both bijective -> each slot written once, RMW'd by exactly one lane.
  asm volatile("s_waitcnt lgkmcnt(0)" ::: "memory");  // same-wave LDS visibility
  __builtin_amdgcn_sched_barrier(0);                  // rule #18: pin the fence
#pragma unroll
  for (int ni = 0; ni < 9; ++ni)
#pragma unroll
    for (int j = 0; j < 4; ++j) {
      int tp  = kq * 4 + j;
      int slw = tp + 127 - (ni * 16 + rq);  // s-window slot this element feeds
      if (slw >= 0 && slw < 128)
        S[tp * 524 + sw + slw] += racc[ni][j];
    }
  __syncthreads();   // B1: S complete across waves

  // ---- softmax (16 threads per row) + x-update ----
  const int row = tid >> 4, tx = tid & 15;
  float p[32];
  float mx = -3.0e38f, l = 0.f;
  {
    const float* Srow = S + row * 524 + tx * 4;
#pragma unroll
    for (int i = 0; i < 8; ++i) {
      float4 v = *(const float4*)(Srow + i * 64);
      p[4*i+0] = v.x; p[4*i+1] = v.y; p[4*i+2] = v.z; p[4*i+3] = v.w;
    }
#pragma unroll
    for (int i = 0; i < 32; ++i) mx = fmaxf(mx, p[i]);
    mx = fmaxf(mx, __shfl_xor(mx, 1)); mx = fmaxf(mx, __shfl_xor(mx, 2));
    mx = fmaxf(mx, __shfl_xor(mx, 4)); mx = fmaxf(mx, __shfl_xor(mx, 8));
#pragma unroll
    for (int i = 0; i < 32; ++i) { p[i] = __expf(p[i] - mx); l += p[i]; }
    l += __shfl_xor(l, 1); l += __shfl_xor(l, 2);
    l += __shfl_xor(l, 4); l += __shfl_xor(l, 8);
  }
  const float invl = 1.0f / l;
  {
    const float xb2c = xb2p[0];
    const float* vxp = vxm + b * TS;
    const float* xp  = xin + (size_t)b * 3 * TS;
    float wsum = 0.f, xa0 = 0.f, xa1 = 0.f, xa2 = 0.f;
#pragma unroll
    for (int i = 0; i < 8; ++i) {
      int s = i * 64 + tx * 4;
      float4 vv = *(const float4*)(vxp + s);
      float4 x0 = *(const float4*)(xp + s);
      float4 x1 = *(const float4*)(xp + TS + s);
      float4 x2 = *(const float4*)(xp + 2 * TS + s);
      float wv;
      wv = p[4*i+0] * (vv.x + xb2c); wsum += wv; xa0 = fmaf(wv, x0.x, xa0); xa1 = fmaf(wv, x1.x, xa1); xa2 = fmaf(wv, x2.x, xa2);
      wv = p[4*i+1] * (vv.y + xb2c); wsum += wv; xa0 = fmaf(wv, x0.y, xa0); xa1 = fmaf(wv, x1.y, xa1); xa2 = fmaf(wv, x2.y, xa2);
      wv = p[4*i+2] * (vv.z + xb2c); wsum += wv; xa0 = fmaf(wv, x0.z, xa0); xa1 = fmaf(wv, x1.z, xa1); xa2 = fmaf(wv, x2.z, xa2);
      wv = p[4*i+3] * (vv.w + xb2c); wsum += wv; xa0 = fmaf(wv, x0.w, xa0); xa1 = fmaf(wv, x1.w, xa1); xa2 = fmaf(wv, x2.w, xa2);
    }
    wsum += __shfl_xor(wsum, 1); wsum += __shfl_xor(wsum, 2);
    wsum += __shfl_xor(wsum, 4); wsum += __shfl_xor(wsum, 8);
    xa0 += __shfl_xor(xa0, 1); xa0 += __shfl_xor(xa0, 2); xa0 += __shfl_xor(xa0, 4); xa0 += __shfl_xor(xa0, 8);
    xa1 += __shfl_xor(xa1, 1); xa1 += __shfl_xor(xa1, 2); xa1 += __shfl_xor(xa1, 4); xa1 += __shfl_xor(xa1, 8);
    xa2 += __shfl_xor(xa2, 1); xa2 += __shfl_xor(xa2, 2); xa2 += __shfl_xor(xa2, 4); xa2 += __shfl_xor(xa2, 8);
    if (tx == 0) {
      int t = t0 + row;
      float ws = wsum * invl;
      xout[(b * 3 + 0) * TS + t] = xp[t]           * (1.0f + ws) - xa0 * invl;
      xout[(b * 3 + 1) * TS + t] = xp[TS + t]      * (1.0f + ws) - xa1 * invl;
      xout[(b * 3 + 2) * TS + t] = xp[2 * TS + t]  * (1.0f + ws) - xa2 * invl;
      sml[row] = invl;
    }
  }
  __syncthreads();   // B2: everyone done reading S -> Pb/Pe may overwrite

  // ---- zero Pe (17408 B = 4352 words, 17/thread) ----
  {
    unsigned int* pz = (unsigned int*)Pe;
#pragma unroll
    for (int i = 0; i < 17; ++i) pz[i * 256 + tid] = 0u;
  }
  __syncthreads();   // B2b: Pe zeroed before scatter

  // ---- scatter P -> Pb (row-major) and Pe (banded: r_local = row+511-s) ----
  {
    unsigned short* pbrow = Pb + row * 520 + tx * 4;
    unsigned short* perow = Pe + row * 544 + row + 511;
#pragma unroll
    for (int i = 0; i < 8; ++i) {
      int s = i * 64 + tx * 4;
      ushort4 pu;
      pu.x = f2h(p[4*i+0]); pu.y = f2h(p[4*i+1]);
      pu.z = f2h(p[4*i+2]); pu.w = f2h(p[4*i+3]);
      *(ushort4*)(pbrow + i * 64) = pu;
      perow[-(s + 0)] = pu.x; perow[-(s + 1)] = pu.y;
      perow[-(s + 2)] = pu.z; perow[-(s + 3)] = pu.w;
    }
  }
  __syncthreads();   // B3: Pb/Pe/sml ready

  // ---- phase 2: O = P@Vt + Pe@embT-band, interleaved prefetched streams ----
  const int n0 = w * 64;
  f32x4 oacc[4];
#pragma unroll
  for (int ni = 0; ni < 4; ++ni) oacc[ni] = (f32x4){0.f, 0.f, 0.f, 0.f};
  {
    const unsigned short* pbp = Pb + rq * 520 + kq * 8;
    const unsigned short* pep = Pe + rq * 544 + kq * 8;
    const unsigned short* vtp = vtH + ((size_t)(b * 256 + n0 + rq) << 9) + kq * 8;
    const unsigned short* etp = embT + (size_t)(n0 + rq) * ETS + t0 + kq * 8;
    f16x8 vA[4], vB[4], gA[4], gB[4];
#pragma unroll
    for (int ni = 0; ni < 4; ++ni) {
      vA[ni] = *(const f16x8*)(vtp + ni * 8192);
      gA[ni] = *(const f16x8*)(etp + ni * 16 * ETS);
      vB[ni] = *(const f16x8*)(vtp + ni * 8192 + 32);
      gB[ni] = *(const f16x8*)(etp + ni * 16 * ETS + 32);
    }
#pragma unroll
    for (int kk = 0; kk < 16; kk += 2) {
      f16x8 pa = *(const f16x8*)(pbp + kk * 32);
      f16x8 pe = *(const f16x8*)(pep + kk * 32);
#pragma unroll
      for (int ni = 0; ni < 4; ++ni) {
        oacc[ni] = __builtin_amdgcn_mfma_f32_16x16x32_f16(pa, vA[ni], oacc[ni], 0, 0, 0);
        if (kk + 2 < 16) vA[ni] = *(const f16x8*)(vtp + ni * 8192 + (kk + 2) * 32);
      }
#pragma unroll
      for (int ni = 0; ni < 4; ++ni) {
        oacc[ni] = __builtin_amdgcn_mfma_f32_16x16x32_f16(pe, gA[ni], oacc[ni], 0, 0, 0);
        if (kk + 2 < 17) gA[ni] = *(const f16x8*)(etp + ni * 16 * ETS + (kk + 2) * 32);
      }
      f16x8 pa2 = *(const f16x8*)(pbp + (kk + 1) * 32);
      f16x8 pe2 = *(const f16x8*)(pep + (kk + 1) * 32);
#pragma unroll
      for (int ni = 0; ni < 4; ++ni) {
        oacc[ni] = __builtin_amdgcn_mfma_f32_16x16x32_f16(pa2, vB[ni], oacc[ni], 0, 0, 0);
        if (kk + 3 < 16) vB[ni] = *(const f16x8*)(vtp + ni * 8192 + (kk + 3) * 32);
      }
#pragma unroll
      for (int ni = 0; ni < 4; ++ni) {
        oacc[ni] = __builtin_amdgcn_mfma_f32_16x16x32_f16(pe2, gB[ni], oacc[ni], 0, 0, 0);
        if (kk + 3 < 17) gB[ni] = *(const f16x8*)(etp + ni * 16 * ETS + (kk + 3) * 32);
      }
    }
    // emb tail ks=16 (gA holds it, loaded at kk=14)
    f16x8 pe16 = *(const f16x8*)(pep + 16 * 32);
#pragma unroll
    for (int ni = 0; ni < 4; ++ni)
      oacc[ni] = __builtin_amdgcn_mfma_f32_16x16x32_f16(pe16, gA[ni], oacc[ni], 0, 0, 0);
  }

  // ---- epilogue: normalize by 1/l, add h residual, coalesced float4 ----
  {
    float il0 = sml[kq * 4 + 0], il1 = sml[kq * 4 + 1];
    float il2 = sml[kq * 4 + 2], il3 = sml[kq * 4 + 3];
#pragma unroll
    for (int ni = 0; ni < 4; ++ni) {
      int hh = n0 + ni * 16 + rq;
      size_t off = (((size_t)(b * 256 + hh)) << 9) + t0 + kq * 4;
      float4 hv = *(const float4*)(hin + off);
      float4 ov;
      ov.x = hv.x + oacc[ni][0] * il0;
      ov.y = hv.y + oacc[ni][1] * il1;
      ov.z = hv.z + oacc[ni][2] * il2;
      ov.w = hv.w + oacc[ni][3] * il3;
      *(float4*)(hout + off) = ov;
    }
  }
}

// ---------------------------------------------------------------------------
extern "C" void kernel_launch(void* const* d_in, const int* in_sizes, int n_in,
                              void* d_out, int out_size, void* d_ws, size_t ws_size,
                              hipStream_t stream)
{
  const float* x   = (const float*)d_in[0];
  const float* h   = (const float*)d_in[1];
  const float* qW1 = (const float*)d_in[2];
  const float* qb1 = (const float*)d_in[3];
  const float* qW2 = (const float*)d_in[4];
  const float* qb2 = (const float*)d_in[5];
  const float* kW1 = (const float*)d_in[6];
  const float* kb1 = (const float*)d_in[7];
  const float* kW2 = (const float*)d_in[8];
  const float* kb2 = (const float*)d_in[9];
  const float* vW1 = (const float*)d_in[10];
  const float* vb1 = (const float*)d_in[11];
  const float* vW2 = (const float*)d_in[12];
  const float* vb2 = (const float*)d_in[13];
  const float* xW1 = (const float*)d_in[14];
  const float* xb1 = (const float*)d_in[15];
  const float* xW2 = (const float*)d_in[16];
  const float* xb2 = (const float*)d_in[17];
  const float* teW = (const float*)d_in[18];
  const float* teb = (const float*)d_in[19];

  // ws layout (fp16 except vx) ~103 MB
  unsigned short* cur = (unsigned short*)d_ws;
  unsigned short* embB = cur; cur += 1024 * 256;
  unsigned short* embT = cur; cur += 256 * ETS;
  unsigned short* hmH  = cur; cur += (size_t)24576 * 256;
  unsigned short* WtH  = cur; cur += 7 * 65536;
  unsigned short* hidQ = cur; cur += (size_t)24576 * 256;
  unsigned short* hidK = cur; cur += (size_t)24576 * 256;
  unsigned short* hidV = cur; cur += (size_t)24576 * 256;
  unsigned short* qHp  = cur; cur += (size_t)24576 * 256;
  unsigned short* kHp  = cur; cur += (size_t)24576 * 256;
  unsigned short* vHp  = cur; cur += (size_t)24576 * 256;
  unsigned short* vtH  = cur; cur += (size_t)24576 * 256;
  float* vx = (float*)cur;                                // 24576 f32

  float* xout = (float*)d_out;                // [48,3,512]
  float* hout = xout + NB * 3 * TS;           // [48,256,512]

  k_embrel<<<1024, 256, 0, stream>>>(teW, teb, embB, embT);
  k_prep_h<<<dim3(4, 8, 48), 256, 0, stream>>>(h, hmH, vx);
  k_prep_w<<<dim3(4, 4, 7), 256, 0, stream>>>(qW1, qW2, kW1, kW2, vW1, vW2, xW1, WtH);

  // layer 1 (q,k,v), layer 2 (q,k,v; v also writes Vt transposed)
  {
    GJobs j1{{{hmH, WtH + 0 * 65536, qb1, hidQ, nullptr, nullptr, nullptr},
              {hmH, WtH + 2 * 65536, kb1, hidK, nullptr, nullptr, nullptr},
              {hmH, WtH + 4 * 65536, vb1, hidV, nullptr, nullptr, nullptr}}};
    k_gemm<1><<<dim3(192, 2, 3), 256, 0, stream>>>(j1);
    GJobs j2{{{hidQ, WtH + 1 * 65536, qb2, qHp, nullptr, nullptr, nullptr},
              {hidK, WtH + 3 * 65536, kb2, kHp, nullptr, nullptr, nullptr},
              {hidV, WtH + 5 * 65536, vb2, vHp, vtH, nullptr, nullptr}}};
    k_gemm<0><<<dim3(192, 2, 3), 256, 0, stream>>>(j2);
  }
  // x-MLP: layer 1 GEMM with fused vx matvec epilogue (no hidden store)
  {
    GJobs j3{{{vHp, WtH + 6 * 65536, xb1, nullptr, nullptr, xW2, vx},
              {}, {}}};
    k_gemm<1><<<dim3(192, 2, 1), 256, 0, stream>>>(j3);
  }

  k_attn3<<<1536, 256, 0, stream>>>(x, h, qHp, kHp, vtH, vx, xb2,
                                    embB, embT, xout, hout);
}